// Round 3
// baseline (61541.425 us; speedup 1.0000x reference)
//
#include <hip/hip_runtime.h>
#include <stdint.h>

#define DEVINL __device__ __forceinline__

constexpr int B_  = 32;
constexpr int S_  = 512;
constexpr int I_  = 768;
constexpr int H_  = 512;
constexpr int C_  = 10;
constexpr int R_  = 64;     // 2 dirs * B_
constexpr int G4H = 2048;   // 4*H_
constexpr int I2_ = 1536;   // 2*I_
constexpr int NBLK = 256;   // persistent grid (1 block/CU co-resident)
constexpr int NTHR = 512;

using bf16x8 = __attribute__((ext_vector_type(8))) short;
using f32x4  = __attribute__((ext_vector_type(4))) float;
typedef unsigned short u16;
typedef unsigned int   u32;

// ---------------- workspace layout (bytes) ----------------
constexpr size_t OFF_TE   = 0;                                   // u16 [B_*S_][H_]  tanh(enc_proj)
constexpr size_t OFF_EMB  = OFF_TE   + (size_t)B_*S_*H_*2;       // u16 [B_*S_][I_]  embeds bf16
constexpr size_t OFF_WDEC = OFF_EMB  + (size_t)B_*S_*I_*2;       // u16 [H_][H_]
constexpr size_t OFF_WHH  = OFF_WDEC + (size_t)H_*H_*2;          // u16 [2][G4H][H_]
constexpr size_t OFF_WIL  = OFF_WHH  + (size_t)2*G4H*H_*2;       // u16 [2][G4H][I_] Wih cols 0..767
constexpr size_t OFF_WIR  = OFF_WIL  + (size_t)2*G4H*I_*2;       // u16 [2][G4H][I_] Wih cols 768..1535
constexpr size_t OFF_WENC = OFF_WIR  + (size_t)2*G4H*I_*2;       // u16 [H_][I_]
constexpr size_t OFF_H    = OFF_WENC + (size_t)H_*I_*2;          // u16 [R_][H_]   h state (bf16)
constexpr size_t OFF_C    = OFF_H    + (size_t)R_*H_*2;          // f32 [R_][H_]   c state
constexpr size_t OFF_TD   = OFF_C    + (size_t)R_*H_*4;          // f32 [R_][H_]   tanh(dec)
constexpr size_t OFF_HWH  = OFF_TD   + (size_t)R_*H_*4;          // f32 [R_][G4H]  h @ Whh^T
constexpr size_t OFF_XW   = OFF_HWH  + (size_t)R_*G4H*4;         // f32 [R_][G4H]  x_t @ WihR^T
constexpr size_t OFF_CTX  = OFF_XW   + (size_t)R_*G4H*4;         // f32 [R_][I_]   unnormalized ctx
constexpr size_t OFF_SUME = OFF_CTX  + (size_t)R_*I_*4;          // f32 [R_]
constexpr size_t OFF_M    = OFF_SUME + 256;                      // f32 [R_] running logsumexp shift
constexpr size_t OFF_BAR  = OFF_M    + 256;                      // u32 [2]: arrive count, generation
constexpr size_t WS_NEED  = OFF_BAR + 64;

// ---------------- helpers ----------------
DEVINL float asf(u32 u){ union{u32 i; float f;} x; x.i=u; return x.f; }
DEVINL u32   asu(float f){ union{u32 i; float f;} x; x.f=f; return x.i; }
DEVINL float bf2f(u16 h){ return asf((u32)h << 16); }
DEVINL u16   f2bf(float f){ u32 u = asu(f); return (u16)((u + 0x7fffu + ((u>>16)&1u)) >> 16); }
DEVINL float frcp(float x){
#if __has_builtin(__builtin_amdgcn_rcpf)
  return __builtin_amdgcn_rcpf(x);
#else
  return 1.0f/x;
#endif
}
DEVINL float sigm(float x){ return frcp(1.0f + __expf(-x)); }

// grid barrier: counter+generation, agent scope. All NBLK blocks co-resident
// (1 block/CU: LDS 29KB, 8 waves) so spin cannot deadlock.
DEVINL void gridbar(u32* bar){
  __syncthreads();
  if (threadIdx.x == 0){
    u32 g = __hip_atomic_load(bar+1, __ATOMIC_RELAXED, __HIP_MEMORY_SCOPE_AGENT);
    __threadfence();   // release this block's phase writes
    u32 a = __hip_atomic_fetch_add(bar, 1u, __ATOMIC_RELAXED, __HIP_MEMORY_SCOPE_AGENT);
    if (a == (u32)NBLK-1u){
      __hip_atomic_store(bar, 0u, __ATOMIC_RELAXED, __HIP_MEMORY_SCOPE_AGENT);
      __threadfence();
      __hip_atomic_store(bar+1, g+1u, __ATOMIC_RELAXED, __HIP_MEMORY_SCOPE_AGENT);
    } else {
      while (__hip_atomic_load(bar+1, __ATOMIC_RELAXED, __HIP_MEMORY_SCOPE_AGENT) == g)
        __builtin_amdgcn_s_sleep(2);
    }
    __threadfence();   // acquire side
  }
  __syncthreads();
}

// ---------------- shared-memory union ----------------
struct SMemB { float ldsE[2][2][32]; float cpart[192][8]; };
struct SMemC { u16 Abuf[16][776]; float Gpre[4][8][16]; float Gs[4][8][16];
               float Hb[8][16]; float inv[8]; float sum[8]; };
union alignas(16) SMem { SMemB b; SMemC c; };

// ---------------- one-time setup: zero state, convert weights ----------------
__global__ void k_setup(char* ws, const float* Wenc, const float* Wdec,
                        const float* Whh_f, const float* Whh_b,
                        const float* Wih_f, const float* Wih_b,
                        float* out){
  int tid = blockIdx.x*blockDim.x + threadIdx.x;
  int nth = gridDim.x*blockDim.x;
  for (int i = tid; i < B_*S_*C_; i += nth) out[i] = 0.f;
  u16* hB = (u16*)(ws+OFF_H);
  for (int i = tid; i < R_*H_; i += nth) hB[i] = 0;
  float* cS = (float*)(ws+OFF_C);
  for (int i = tid; i < R_*H_; i += nth) cS[i] = 0.f;
  float* mb = (float*)(ws+OFF_M);
  for (int i = tid; i < R_; i += nth) mb[i] = 0.f;
  u32* bar = (u32*)(ws+OFF_BAR);
  if (tid < 2) bar[tid] = 0u;
  u16* wd = (u16*)(ws+OFF_WDEC);
  for (int i = tid; i < H_*H_; i += nth) wd[i] = f2bf(Wdec[i]);
  u16* we = (u16*)(ws+OFF_WENC);
  for (int i = tid; i < H_*I_; i += nth) we[i] = f2bf(Wenc[i]);
  u16* wh = (u16*)(ws+OFF_WHH);
  for (int i = tid; i < G4H*H_; i += nth){
    wh[i] = f2bf(Whh_f[i]);
    wh[G4H*H_ + i] = f2bf(Whh_b[i]);
  }
  u16* wl = (u16*)(ws+OFF_WIL);
  u16* wr = (u16*)(ws+OFF_WIR);
  for (int i = tid; i < G4H*I_; i += nth){
    int n = i / I_, k = i - n*I_;
    wl[i]            = f2bf(Wih_f[n*I2_ + k]);
    wr[i]            = f2bf(Wih_f[n*I2_ + I_ + k]);
    wl[G4H*I_ + i]   = f2bf(Wih_b[n*I2_ + k]);
    wr[G4H*I_ + i]   = f2bf(Wih_b[n*I2_ + I_ + k]);
  }
}

// ---------------- one-time: embeds -> bf16 ----------------
__global__ void k_embconv(char* ws, const float* emb){
  u16* e = (u16*)(ws+OFF_EMB);
  int tid = blockIdx.x*blockDim.x + threadIdx.x;
  int nth = gridDim.x*blockDim.x;
  int n4 = (B_*S_*I_)/4;
  const float4* src = (const float4*)emb;
  ushort4* dst = (ushort4*)e;
  for (int i = tid; i < n4; i += nth){
    float4 x = src[i];
    ushort4 o;
    o.x = f2bf(x.x); o.y = f2bf(x.y); o.z = f2bf(x.z); o.w = f2bf(x.w);
    dst[i] = o;
  }
}

// ---------------- one-time: Te = tanh(embB @ WencB^T + benc) ----------------
__global__ __launch_bounds__(256) void k_enc(char* ws, const float* benc){
  const u16* A = (const u16*)(ws+OFF_EMB);
  const u16* W = (const u16*)(ws+OFF_WENC);
  u16* Te = (u16*)(ws+OFF_TE);
  int wg = blockIdx.x;
  int mt = wg >> 3, ng = wg & 7;
  int wave = threadIdx.x >> 6, lane = threadIdx.x & 63;
  int m0 = mt*16, n0 = ng*64 + wave*16;
  int lr = lane & 15, lkb = (lane>>4)*8;
  const u16* ap = A + (size_t)(m0+lr)*I_ + lkb;
  const u16* bp = W + (size_t)(n0+lr)*I_ + lkb;
  f32x4 acc = {0.f,0.f,0.f,0.f};
  for (int k = 0; k < I_; k += 32){
    bf16x8 a = *(const bf16x8*)(ap + k);
    bf16x8 b = *(const bf16x8*)(bp + k);
    acc = __builtin_amdgcn_mfma_f32_16x16x32_bf16(a, b, acc, 0, 0, 0);
  }
  int row4 = (lane>>4)*4;
  #pragma unroll
  for (int q = 0; q < 4; q++){
    int rr = m0 + row4 + q, cc = n0 + lr;
    Te[(size_t)rr*H_ + cc] = f2bf(tanhf(acc[q] + benc[cc]));
  }
}

// ---------------- persistent stepper: 512 steps, 3 grid barriers/step ----------------
__global__ __launch_bounds__(NTHR) void k_persist(char* ws,
        const float* bdec, const float* v,
        const float* bih_f, const float* bhh_f,
        const float* bih_b, const float* bhh_b,
        const float* Wout, const float* bout, float* out){
  __shared__ SMem sh;
  u32* bar = (u32*)(ws+OFF_BAR);
  const int tid = threadIdx.x, lane = tid & 63, wave = tid >> 6;
  const int lr = lane & 15, lkb = (lane>>4)*8, row4 = (lane>>4)*4;

  // zero Abuf once; rows 8..15 (bytes 12416..24831) are never clobbered by
  // phase B (its struct spans only the first 6656 bytes) and rows 0..7 are
  // rewritten every step, so this establishes permanent zero-padding rows.
  for (int i = tid; i < 16*776; i += NTHR) ((u16*)sh.c.Abuf)[i] = 0;
  __syncthreads();

  for (int t = 0; t < S_; ++t){
    // ================= phase A: dec/Td, h@Whh^T, x_t@WihR^T; zero ctx/sumE =================
    {
      int gw = blockIdx.x*8 + wave;     // 0..2047
      const u16* hB = (const u16*)(ws+OFF_H);
      if (gw < 128){                    // dec: M=64, N=512, K=512
        int m0 = (gw>>5)*16, n0 = (gw&31)*16;
        const u16* W = (const u16*)(ws+OFF_WDEC);
        const u16* ap = hB + (size_t)(m0+lr)*H_ + lkb;
        const u16* bp = W + (size_t)(n0+lr)*H_ + lkb;
        f32x4 acc = {0.f,0.f,0.f,0.f};
        for (int k = 0; k < H_; k += 32){
          bf16x8 a = *(const bf16x8*)(ap + k);
          bf16x8 b = *(const bf16x8*)(bp + k);
          acc = __builtin_amdgcn_mfma_f32_16x16x32_bf16(a, b, acc, 0, 0, 0);
        }
        float* Td = (float*)(ws+OFF_TD);
        #pragma unroll
        for (int q = 0; q < 4; q++){
          int rr = m0 + row4 + q, cc = n0 + lr;
          Td[rr*H_ + cc] = tanhf(acc[q] + bdec[cc]);
        }
      } else if (gw < 640){             // hWhh: per dir M=32, N=2048, K=512
        int t2 = gw - 128; int dir = t2 >> 8; int t3 = t2 & 255;
        int m0 = dir*32 + (t3>>7)*16;
        int n0 = (t3 & 127)*16;
        const u16* W = (const u16*)(ws+OFF_WHH) + (size_t)dir*G4H*H_;
        const u16* ap = hB + (size_t)(m0+lr)*H_ + lkb;
        const u16* bp = W + (size_t)(n0+lr)*H_ + lkb;
        f32x4 acc = {0.f,0.f,0.f,0.f};
        for (int k = 0; k < H_; k += 32){
          bf16x8 a = *(const bf16x8*)(ap + k);
          bf16x8 b = *(const bf16x8*)(bp + k);
          acc = __builtin_amdgcn_mfma_f32_16x16x32_bf16(a, b, acc, 0, 0, 0);
        }
        float* o = (float*)(ws+OFF_HWH);
        #pragma unroll
        for (int q = 0; q < 4; q++){
          int rr = m0 + row4 + q;
          o[(size_t)rr*G4H + n0 + lr] = acc[q];
        }
      } else if (gw < 1152){            // xW: per dir M=32, N=2048, K=768
        int t2 = gw - 640; int dir = t2 >> 8; int t3 = t2 & 255;
        int bbase = (t3>>7)*16;
        int n0 = (t3 & 127)*16;
        int trow = dir ? (S_-1-t) : t;
        const u16* E = (const u16*)(ws+OFF_EMB);
        const u16* W = (const u16*)(ws+OFF_WIR) + (size_t)dir*G4H*I_;
        const u16* ap = E + ((size_t)(bbase+lr)*S_ + trow)*I_ + lkb;
        const u16* bp = W + (size_t)(n0+lr)*I_ + lkb;
        f32x4 acc = {0.f,0.f,0.f,0.f};
        for (int k = 0; k < I_; k += 32){
          bf16x8 a = *(const bf16x8*)(ap + k);
          bf16x8 b = *(const bf16x8*)(bp + k);
          acc = __builtin_amdgcn_mfma_f32_16x16x32_bf16(a, b, acc, 0, 0, 0);
        }
        float* o = (float*)(ws+OFF_XW);
        #pragma unroll
        for (int q = 0; q < 4; q++){
          int bb = bbase + row4 + q;
          o[(size_t)(dir*32+bb)*G4H + n0 + lr] = acc[q];
        }
      } else {                          // zero ctx & sumE for this step
        int zid = (gw - 1152)*64 + lane;      // 0..57343 covers 49152+64
        float* ctx = (float*)(ws+OFF_CTX);
        if (zid < R_*I_) ctx[zid] = 0.f;
        if (zid < R_) ((float*)(ws+OFF_SUME))[zid] = 0.f;
      }
    }
    gridbar(bar);
    // ================= phase B: scores via tanh-identity, exp, ctx partials =================
    {
      int wg = blockIdx.x;
      int b = wg & 31, pair = wg >> 5;
      int s0A = pair*32, s0B = S_ - pair*32 - 32;
      const u16* Te = (const u16*)(ws+OFF_TE);
      const float* Td = (const float*)(ws+OFF_TD);
      const float* mbp = (const float*)(ws+OFF_M);
      int h0 = lane*8;
      float tdf[8], tdb[8], va[8];
      #pragma unroll
      for (int j = 0; j < 8; j++){
        tdf[j] = Td[b*H_ + h0 + j];
        tdb[j] = Td[(32+b)*H_ + h0 + j];
        va[j]  = v[h0 + j];
      }
      float mF = mbp[b], mB = mbp[32+b];
      #pragma unroll 2
      for (int r = wave; r < 64; r += 8){
        int ci = r >> 5, u = r & 31;
        int s = (ci ? s0B : s0A) + u;
        const uint4 tv = *(const uint4*)(Te + ((size_t)(b*S_ + s))*H_ + h0);
        u32 wv[4] = {tv.x, tv.y, tv.z, tv.w};
        float af = 0.f, ab = 0.f;
        #pragma unroll
        for (int q = 0; q < 4; q++){
          int j = 2*q;
          float te0 = asf(wv[q] << 16);
          float te1 = asf(wv[q] & 0xffff0000u);
          float d0f = fmaf(te0, tdf[j],   1.0f);
          float d0b = fmaf(te0, tdb[j],   1.0f);
          af = fmaf((te0+tdf[j])*frcp(d0f), va[j], af);
          ab = fmaf((te0+tdb[j])*frcp(d0b), va[j], ab);
          float d1f = fmaf(te1, tdf[j+1], 1.0f);
          float d1b = fmaf(te1, tdb[j+1], 1.0f);
          af = fmaf((te1+tdf[j+1])*frcp(d1f), va[j+1], af);
          ab = fmaf((te1+tdb[j+1])*frcp(d1b), va[j+1], ab);
        }
        #pragma unroll
        for (int off = 1; off < 64; off <<= 1){
          af += __shfl_xor(af, off);
          ab += __shfl_xor(ab, off);
        }
        float ef = __expf(fminf(fmaxf(af - mF, -80.f), 80.f));
        float eb = __expf(fminf(fmaxf(ab - mB, -80.f), 80.f));
        if (lane == 0){ sh.b.ldsE[0][ci][u] = ef; sh.b.ldsE[1][ci][u] = eb; }
      }
      __syncthreads();
      if (tid < 2){
        float s = 0.f;
        for (int ci = 0; ci < 2; ci++)
          for (int u = 0; u < 32; u++) s += sh.b.ldsE[tid][ci][u];
        atomicAdd((float*)(ws+OFF_SUME) + tid*32 + b, s);
      }
      float cf[4] = {0.f,0.f,0.f,0.f}, cb[4] = {0.f,0.f,0.f,0.f};
      if (tid < 384){
        int hf = (tid >= 192) ? 1 : 0;
        int t2 = hf ? tid-192 : tid;
        int i0 = t2*4;
        const u16* E = (const u16*)(ws+OFF_EMB);
        int sbase = hf ? s0B : s0A;
        #pragma unroll 4
        for (int u = 0; u < 32; u++){
          ushort4 x4 = *(const ushort4*)(E + ((size_t)(b*S_ + sbase + u))*I_ + i0);
          float wf = sh.b.ldsE[0][hf][u];
          float wb = sh.b.ldsE[1][1-hf][31-u];   // emb[s] pairs with e_b[S-1-s]
          float x0 = bf2f(x4.x), x1 = bf2f(x4.y), x2 = bf2f(x4.z), x3 = bf2f(x4.w);
          cf[0] = fmaf(wf, x0, cf[0]); cf[1] = fmaf(wf, x1, cf[1]);
          cf[2] = fmaf(wf, x2, cf[2]); cf[3] = fmaf(wf, x3, cf[3]);
          cb[0] = fmaf(wb, x0, cb[0]); cb[1] = fmaf(wb, x1, cb[1]);
          cb[2] = fmaf(wb, x2, cb[2]); cb[3] = fmaf(wb, x3, cb[3]);
        }
        if (hf){
          #pragma unroll
          for (int z = 0; z < 4; z++){
            sh.b.cpart[t2][z]   = cf[z];
            sh.b.cpart[t2][4+z] = cb[z];
          }
        }
      }
      __syncthreads();
      if (tid < 192){
        float* ctx = (float*)(ws+OFF_CTX);
        int i0 = tid*4;
        #pragma unroll
        for (int z = 0; z < 4; z++){
          atomicAdd(&ctx[(size_t)b*I_ + i0 + z],      cf[z] + sh.b.cpart[tid][z]);
          atomicAdd(&ctx[(size_t)(32+b)*I_ + i0 + z], cb[z] + sh.b.cpart[tid][4+z]);
        }
      }
    }
    gridbar(bar);
    // ================= phase C: ctx@WihL^T, LSTM cell, out projection =================
    {
      int blk = blockIdx.x;
      int dir = blk >> 7, rest = blk & 127, hc = rest >> 2, qb = rest & 3;
      int rb0 = qb*8;
      const float* se = (const float*)(ws+OFF_SUME) + dir*32;
      if (tid < 8){
        float s_ = se[rb0 + tid];
        sh.c.sum[tid] = s_;
        sh.c.inv[tid] = 1.0f / fmaxf(s_, 1e-30f);
      }
      __syncthreads();
      const float* ctx = (const float*)(ws+OFF_CTX) + (size_t)dir*32*I_;
      for (int idx = tid; idx < 8*I_; idx += NTHR){
        int j = idx / I_, k = idx - j*I_;
        sh.c.Abuf[j][k] = f2bf(ctx[(size_t)(rb0+j)*I_ + k] * sh.c.inv[j]);
      }
      __syncthreads();
      f32x4 acc = {0.f,0.f,0.f,0.f};
      if (wave < 4){
        int gt = wave;
        const u16* Wp = (const u16*)(ws+OFF_WIL) + (size_t)dir*G4H*I_;
        int n_g = gt*512 + hc*16 + lr;
        const u16* bp = Wp + (size_t)n_g*I_ + lkb;
        for (int k = 0; k < I_; k += 32){
          bf16x8 av = *(const bf16x8*)(&sh.c.Abuf[lr][k + lkb]);
          bf16x8 bv = *(const bf16x8*)(bp + k);
          acc = __builtin_amdgcn_mfma_f32_16x16x32_bf16(av, bv, acc, 0, 0, 0);
        }
      } else {
        int gt = wave - 4;
        const float* xW = (const float*)(ws+OFF_XW);
        const float* hW = (const float*)(ws+OFF_HWH);
        const float* bih = dir ? bih_b : bih_f;
        const float* bhh = dir ? bhh_b : bhh_f;
        int j0 = lane >> 4, col = lane & 15;
        int n = gt*512 + hc*16 + col;
        #pragma unroll
        for (int jj = j0; jj < 8; jj += 4){
          size_t rr = (size_t)(dir*32 + rb0 + jj);
          sh.c.Gpre[gt][jj][col] = xW[rr*G4H + n] + hW[rr*G4H + n] + bih[n] + bhh[n];
        }
      }
      __syncthreads();
      if (wave < 4){
        int gt = wave, col = lane & 15;
        #pragma unroll
        for (int q = 0; q < 4; q++){
          int row = row4 + q;
          if (row < 8) sh.c.Gs[gt][row][col] = acc[q] + sh.c.Gpre[gt][row][col];
        }
      }
      __syncthreads();
      float* cS = (float*)(ws+OFF_C);
      u16* hBw = (u16*)(ws+OFF_H);
      if (tid < 128){
        int j = tid >> 4, col = tid & 15;
        int hg = hc*16 + col;
        size_t rr = (size_t)(dir*32 + rb0 + j);
        float ig = sigm(sh.c.Gs[0][j][col]);
        float fg = sigm(sh.c.Gs[1][j][col]);
        float gg = tanhf(sh.c.Gs[2][j][col]);
        float og = sigm(sh.c.Gs[3][j][col]);
        float cn = fmaf(fg, cS[rr*H_ + hg], ig*gg);
        float hn = og * tanhf(cn);
        cS[rr*H_ + hg] = cn;
        hBw[rr*H_ + hg] = f2bf(hn);
        sh.c.Hb[j][col] = hn;
      }
      __syncthreads();
      if (tid < 80){
        int bb = tid/10, cc = tid - bb*10;
        const float* wr = Wout + (size_t)cc*1024 + dir*512 + hc*16;
        float s = 0.f;
        #pragma unroll
        for (int j = 0; j < 16; j++) s = fmaf(sh.c.Hb[bb][j], wr[j], s);
        if (dir == 0 && hc == 0) s += bout[cc];
        int st = dir ? (S_-1-t) : t;
        atomicAdd(&out[((size_t)(qb*8+bb)*S_ + st)*C_ + cc], s);
      }
      if (hc == 0 && tid < 8){
        float* mbp = (float*)(ws+OFF_M);
        mbp[dir*32 + rb0 + tid] += logf(fmaxf(sh.c.sum[tid], 1e-30f));
      }
    }
    gridbar(bar);
  }
}

// ---------------- host launcher ----------------
extern "C" void kernel_launch(void* const* d_in, const int* in_sizes, int n_in,
                              void* d_out, int out_size, void* d_ws, size_t ws_size,
                              hipStream_t stream){
  const float* emb   = (const float*)d_in[0];
  const float* Wenc  = (const float*)d_in[1];
  const float* benc  = (const float*)d_in[2];
  const float* Wdec  = (const float*)d_in[3];
  const float* bdec  = (const float*)d_in[4];
  const float* v     = (const float*)d_in[5];
  const float* Wih_f = (const float*)d_in[6];
  const float* Whh_f = (const float*)d_in[7];
  const float* bih_f = (const float*)d_in[8];
  const float* bhh_f = (const float*)d_in[9];
  const float* Wih_b = (const float*)d_in[10];
  const float* Whh_b = (const float*)d_in[11];
  const float* bih_b = (const float*)d_in[12];
  const float* bhh_b = (const float*)d_in[13];
  const float* Wout  = (const float*)d_in[14];
  const float* bout  = (const float*)d_in[15];
  float* out = (float*)d_out;
  char* ws = (char*)d_ws;
  if (ws_size < WS_NEED) return;   // fail loudly via validation

  k_setup<<<dim3(512), dim3(256), 0, stream>>>(ws, Wenc, Wdec, Whh_f, Whh_b, Wih_f, Wih_b, out);
  k_embconv<<<dim3(2048), dim3(256), 0, stream>>>(ws, emb);
  k_enc<<<dim3(8192), dim3(256), 0, stream>>>(ws, benc);
  k_persist<<<dim3(NBLK), dim3(NTHR), 0, stream>>>(ws, bdec, v,
      bih_f, bhh_f, bih_b, bhh_b, Wout, bout, out);
}

// Round 4
// 34893.311 us; speedup vs baseline: 1.7637x; 1.7637x over previous
//
#include <hip/hip_runtime.h>
#include <stdint.h>

#define DEVINL __device__ __forceinline__

constexpr int B_  = 32;
constexpr int S_  = 512;
constexpr int I_  = 768;
constexpr int H_  = 512;
constexpr int C_  = 10;
constexpr int R_  = 64;     // 2 dirs * B_
constexpr int G4H = 2048;   // 4*H_
constexpr int I2_ = 1536;   // 2*I_
constexpr int NBLK = 256;   // persistent grid (1 block/CU co-resident)
constexpr int NTHR = 512;

using bf16x8 = __attribute__((ext_vector_type(8))) short;
using f32x4  = __attribute__((ext_vector_type(4))) float;
typedef unsigned short u16;
typedef unsigned int   u32;

// ---------------- workspace layout (bytes) ----------------
constexpr size_t OFF_TE   = 0;                                   // u16 [B_*S_][H_]  tanh(enc_proj)
constexpr size_t OFF_EMB  = OFF_TE   + (size_t)B_*S_*H_*2;       // u16 [B_*S_][I_]  embeds bf16
constexpr size_t OFF_WDEC = OFF_EMB  + (size_t)B_*S_*I_*2;       // u16 [H_][H_]
constexpr size_t OFF_WHH  = OFF_WDEC + (size_t)H_*H_*2;          // u16 [2][G4H][H_]
constexpr size_t OFF_WIL  = OFF_WHH  + (size_t)2*G4H*H_*2;       // u16 [2][G4H][I_] Wih cols 0..767
constexpr size_t OFF_WIR  = OFF_WIL  + (size_t)2*G4H*I_*2;       // u16 [2][G4H][I_] Wih cols 768..1535
constexpr size_t OFF_WENC = OFF_WIR  + (size_t)2*G4H*I_*2;       // u16 [H_][I_]
constexpr size_t OFF_H    = OFF_WENC + (size_t)H_*I_*2;          // u16 [R_][H_]   h state (bf16)
constexpr size_t OFF_C    = OFF_H    + (size_t)R_*H_*2;          // f32 [R_][H_]   c state
constexpr size_t OFF_TD   = OFF_C    + (size_t)R_*H_*4;          // f32 [R_][H_]   tanh(dec)
constexpr size_t OFF_HWH  = OFF_TD   + (size_t)R_*H_*4;          // f32 [R_][G4H]  h @ Whh^T
constexpr size_t OFF_XW   = OFF_HWH  + (size_t)R_*G4H*4;         // f32 [R_][G4H]  x_t @ WihR^T
constexpr size_t OFF_CTX  = OFF_XW   + (size_t)R_*G4H*4;         // f32 [R_][I_]   unnormalized ctx
constexpr size_t OFF_SUME = OFF_CTX  + (size_t)R_*I_*4;          // f32 [R_]
constexpr size_t OFF_M    = OFF_SUME + 256;                      // f32 [R_] running logsumexp shift
// barrier: u32 words. [0..31] root line; [32..63] generation line;
// [64 + g*32] group-g counter line (g = 0..31). All monotonic, zeroed per launch.
constexpr size_t OFF_BAR  = OFF_M    + 256;
constexpr int    BAR_W    = 64 + 32*32;                          // 1088 u32 words
constexpr size_t WS_NEED  = OFF_BAR + BAR_W*4;

// ---------------- helpers ----------------
DEVINL float asf(u32 u){ union{u32 i; float f;} x; x.i=u; return x.f; }
DEVINL u32   asu(float f){ union{u32 i; float f;} x; x.f=f; return x.i; }
DEVINL float bf2f(u16 h){ return asf((u32)h << 16); }
DEVINL u16   f2bf(float f){ u32 u = asu(f); return (u16)((u + 0x7fffu + ((u>>16)&1u)) >> 16); }
DEVINL float frcp(float x){
#if __has_builtin(__builtin_amdgcn_rcpf)
  return __builtin_amdgcn_rcpf(x);
#else
  return 1.0f/x;
#endif
}
DEVINL float sigm(float x){ return frcp(1.0f + __expf(-x)); }

// grid barrier, 2-level tree with monotonic targets (n = 1-based barrier idx):
//   group g (8 blocks, own cacheline): fetch_add; last (old == 8n-1) bumps root.
//   root (32 arrivals): last (old == 32n-1) publishes generation = n.
//   everyone spins on the generation word (read-only hot line, cheap).
// Avoids R3's 256-RMW-on-one-line serialization (~30us/barrier -> ~2-4us).
DEVINL void gridbar(u32* bar, u32 n){
  __syncthreads();
  if (threadIdx.x == 0){
    __threadfence();   // release this block's phase writes
    u32 g = blockIdx.x >> 3;
    u32 old = __hip_atomic_fetch_add(&bar[64 + g*32], 1u, __ATOMIC_RELAXED, __HIP_MEMORY_SCOPE_AGENT);
    if (old == n*8u - 1u){
      u32 r = __hip_atomic_fetch_add(&bar[0], 1u, __ATOMIC_RELAXED, __HIP_MEMORY_SCOPE_AGENT);
      if (r == n*32u - 1u){
        __hip_atomic_store(&bar[32], n, __ATOMIC_RELAXED, __HIP_MEMORY_SCOPE_AGENT);
      }
    }
    while (__hip_atomic_load(&bar[32], __ATOMIC_RELAXED, __HIP_MEMORY_SCOPE_AGENT) < n)
      __builtin_amdgcn_s_sleep(8);
    __threadfence();   // acquire side
  }
  __syncthreads();
}

// ---------------- shared-memory union ----------------
struct SMemB { float ldsE[2][2][32]; float cpart[192][8]; };
struct SMemC { u16 Abuf[16][776]; float Gpre[4][8][16]; float Gs[4][8][16];
               float Hb[8][16]; float inv[8]; float sum[8]; };
union alignas(16) SMem { SMemB b; SMemC c; };

// ---------------- one-time setup: zero state, convert weights ----------------
__global__ void k_setup(char* ws, const float* Wenc, const float* Wdec,
                        const float* Whh_f, const float* Whh_b,
                        const float* Wih_f, const float* Wih_b,
                        float* out){
  int tid = blockIdx.x*blockDim.x + threadIdx.x;
  int nth = gridDim.x*blockDim.x;
  for (int i = tid; i < B_*S_*C_; i += nth) out[i] = 0.f;
  u16* hB = (u16*)(ws+OFF_H);
  for (int i = tid; i < R_*H_; i += nth) hB[i] = 0;
  float* cS = (float*)(ws+OFF_C);
  for (int i = tid; i < R_*H_; i += nth) cS[i] = 0.f;
  float* mb = (float*)(ws+OFF_M);
  for (int i = tid; i < R_; i += nth) mb[i] = 0.f;
  u32* bar = (u32*)(ws+OFF_BAR);
  for (int i = tid; i < BAR_W; i += nth) bar[i] = 0u;
  u16* wd = (u16*)(ws+OFF_WDEC);
  for (int i = tid; i < H_*H_; i += nth) wd[i] = f2bf(Wdec[i]);
  u16* we = (u16*)(ws+OFF_WENC);
  for (int i = tid; i < H_*I_; i += nth) we[i] = f2bf(Wenc[i]);
  u16* wh = (u16*)(ws+OFF_WHH);
  for (int i = tid; i < G4H*H_; i += nth){
    wh[i] = f2bf(Whh_f[i]);
    wh[G4H*H_ + i] = f2bf(Whh_b[i]);
  }
  u16* wl = (u16*)(ws+OFF_WIL);
  u16* wr = (u16*)(ws+OFF_WIR);
  for (int i = tid; i < G4H*I_; i += nth){
    int n = i / I_, k = i - n*I_;
    wl[i]            = f2bf(Wih_f[n*I2_ + k]);
    wr[i]            = f2bf(Wih_f[n*I2_ + I_ + k]);
    wl[G4H*I_ + i]   = f2bf(Wih_b[n*I2_ + k]);
    wr[G4H*I_ + i]   = f2bf(Wih_b[n*I2_ + I_ + k]);
  }
}

// ---------------- one-time: embeds -> bf16 ----------------
__global__ void k_embconv(char* ws, const float* emb){
  u16* e = (u16*)(ws+OFF_EMB);
  int tid = blockIdx.x*blockDim.x + threadIdx.x;
  int nth = gridDim.x*blockDim.x;
  int n4 = (B_*S_*I_)/4;
  const float4* src = (const float4*)emb;
  ushort4* dst = (ushort4*)e;
  for (int i = tid; i < n4; i += nth){
    float4 x = src[i];
    ushort4 o;
    o.x = f2bf(x.x); o.y = f2bf(x.y); o.z = f2bf(x.z); o.w = f2bf(x.w);
    dst[i] = o;
  }
}

// ---------------- one-time: Te = tanh(embB @ WencB^T + benc) ----------------
__global__ __launch_bounds__(256) void k_enc(char* ws, const float* benc){
  const u16* A = (const u16*)(ws+OFF_EMB);
  const u16* W = (const u16*)(ws+OFF_WENC);
  u16* Te = (u16*)(ws+OFF_TE);
  int wg = blockIdx.x;
  int mt = wg >> 3, ng = wg & 7;
  int wave = threadIdx.x >> 6, lane = threadIdx.x & 63;
  int m0 = mt*16, n0 = ng*64 + wave*16;
  int lr = lane & 15, lkb = (lane>>4)*8;
  const u16* ap = A + (size_t)(m0+lr)*I_ + lkb;
  const u16* bp = W + (size_t)(n0+lr)*I_ + lkb;
  f32x4 acc = {0.f,0.f,0.f,0.f};
  for (int k = 0; k < I_; k += 32){
    bf16x8 a = *(const bf16x8*)(ap + k);
    bf16x8 b = *(const bf16x8*)(bp + k);
    acc = __builtin_amdgcn_mfma_f32_16x16x32_bf16(a, b, acc, 0, 0, 0);
  }
  int row4 = (lane>>4)*4;
  #pragma unroll
  for (int q = 0; q < 4; q++){
    int rr = m0 + row4 + q, cc = n0 + lr;
    Te[(size_t)rr*H_ + cc] = f2bf(tanhf(acc[q] + benc[cc]));
  }
}

// ---------------- persistent stepper: 512 steps, 3 grid barriers/step ----------------
__global__ __launch_bounds__(NTHR) void k_persist(char* ws,
        const float* bdec, const float* v,
        const float* bih_f, const float* bhh_f,
        const float* bih_b, const float* bhh_b,
        const float* Wout, const float* bout, float* out){
  __shared__ SMem sh;
  u32* bar = (u32*)(ws+OFF_BAR);
  u32 gen = 0;
  const int tid = threadIdx.x, lane = tid & 63, wave = tid >> 6;
  const int lr = lane & 15, lkb = (lane>>4)*8, row4 = (lane>>4)*4;

  // zero Abuf once; rows 8..15 (bytes 12416..24831) are never clobbered by
  // phase B (its struct spans only the first 6656 bytes) and rows 0..7 are
  // rewritten every step, so this establishes permanent zero-padding rows.
  for (int i = tid; i < 16*776; i += NTHR) ((u16*)sh.c.Abuf)[i] = 0;
  __syncthreads();

  for (int t = 0; t < S_; ++t){
    // ================= phase A: dec/Td, h@Whh^T, x_t@WihR^T; zero ctx/sumE =================
    {
      int gw = blockIdx.x*8 + wave;     // 0..2047
      const u16* hB = (const u16*)(ws+OFF_H);
      if (gw < 128){                    // dec: M=64, N=512, K=512
        int m0 = (gw>>5)*16, n0 = (gw&31)*16;
        const u16* W = (const u16*)(ws+OFF_WDEC);
        const u16* ap = hB + (size_t)(m0+lr)*H_ + lkb;
        const u16* bp = W + (size_t)(n0+lr)*H_ + lkb;
        f32x4 acc = {0.f,0.f,0.f,0.f};
        for (int k = 0; k < H_; k += 32){
          bf16x8 a = *(const bf16x8*)(ap + k);
          bf16x8 b = *(const bf16x8*)(bp + k);
          acc = __builtin_amdgcn_mfma_f32_16x16x32_bf16(a, b, acc, 0, 0, 0);
        }
        float* Td = (float*)(ws+OFF_TD);
        #pragma unroll
        for (int q = 0; q < 4; q++){
          int rr = m0 + row4 + q, cc = n0 + lr;
          Td[rr*H_ + cc] = tanhf(acc[q] + bdec[cc]);
        }
      } else if (gw < 640){             // hWhh: per dir M=32, N=2048, K=512
        int t2 = gw - 128; int dir = t2 >> 8; int t3 = t2 & 255;
        int m0 = dir*32 + (t3>>7)*16;
        int n0 = (t3 & 127)*16;
        const u16* W = (const u16*)(ws+OFF_WHH) + (size_t)dir*G4H*H_;
        const u16* ap = hB + (size_t)(m0+lr)*H_ + lkb;
        const u16* bp = W + (size_t)(n0+lr)*H_ + lkb;
        f32x4 acc = {0.f,0.f,0.f,0.f};
        for (int k = 0; k < H_; k += 32){
          bf16x8 a = *(const bf16x8*)(ap + k);
          bf16x8 b = *(const bf16x8*)(bp + k);
          acc = __builtin_amdgcn_mfma_f32_16x16x32_bf16(a, b, acc, 0, 0, 0);
        }
        float* o = (float*)(ws+OFF_HWH);
        #pragma unroll
        for (int q = 0; q < 4; q++){
          int rr = m0 + row4 + q;
          o[(size_t)rr*G4H + n0 + lr] = acc[q];
        }
      } else if (gw < 1152){            // xW: per dir M=32, N=2048, K=768
        int t2 = gw - 640; int dir = t2 >> 8; int t3 = t2 & 255;
        int bbase = (t3>>7)*16;
        int n0 = (t3 & 127)*16;
        int trow = dir ? (S_-1-t) : t;
        const u16* E = (const u16*)(ws+OFF_EMB);
        const u16* W = (const u16*)(ws+OFF_WIR) + (size_t)dir*G4H*I_;
        const u16* ap = E + ((size_t)(bbase+lr)*S_ + trow)*I_ + lkb;
        const u16* bp = W + (size_t)(n0+lr)*I_ + lkb;
        f32x4 acc = {0.f,0.f,0.f,0.f};
        for (int k = 0; k < I_; k += 32){
          bf16x8 a = *(const bf16x8*)(ap + k);
          bf16x8 b = *(const bf16x8*)(bp + k);
          acc = __builtin_amdgcn_mfma_f32_16x16x32_bf16(a, b, acc, 0, 0, 0);
        }
        float* o = (float*)(ws+OFF_XW);
        #pragma unroll
        for (int q = 0; q < 4; q++){
          int bb = bbase + row4 + q;
          o[(size_t)(dir*32+bb)*G4H + n0 + lr] = acc[q];
        }
      } else {                          // zero ctx & sumE for this step
        int zid = (gw - 1152)*64 + lane;      // covers 49152+64
        float* ctx = (float*)(ws+OFF_CTX);
        if (zid < R_*I_) ctx[zid] = 0.f;
        if (zid < R_) ((float*)(ws+OFF_SUME))[zid] = 0.f;
      }
    }
    gridbar(bar, ++gen);
    // ================= phase B: scores via tanh-identity, exp, ctx partials =================
    {
      int wg = blockIdx.x;
      int b = wg & 31, pair = wg >> 5;
      int s0A = pair*32, s0B = S_ - pair*32 - 32;
      const u16* Te = (const u16*)(ws+OFF_TE);
      const float* Td = (const float*)(ws+OFF_TD);
      const float* mbp = (const float*)(ws+OFF_M);
      int h0 = lane*8;
      float tdf[8], tdb[8], va[8];
      #pragma unroll
      for (int j = 0; j < 8; j++){
        tdf[j] = Td[b*H_ + h0 + j];
        tdb[j] = Td[(32+b)*H_ + h0 + j];
        va[j]  = v[h0 + j];
      }
      float mF = mbp[b], mB = mbp[32+b];
      #pragma unroll 2
      for (int r = wave; r < 64; r += 8){
        int ci = r >> 5, u = r & 31;
        int s = (ci ? s0B : s0A) + u;
        const uint4 tv = *(const uint4*)(Te + ((size_t)(b*S_ + s))*H_ + h0);
        u32 wv[4] = {tv.x, tv.y, tv.z, tv.w};
        float af = 0.f, ab = 0.f;
        #pragma unroll
        for (int q = 0; q < 4; q++){
          int j = 2*q;
          float te0 = asf(wv[q] << 16);
          float te1 = asf(wv[q] & 0xffff0000u);
          float d0f = fmaf(te0, tdf[j],   1.0f);
          float d0b = fmaf(te0, tdb[j],   1.0f);
          af = fmaf((te0+tdf[j])*frcp(d0f), va[j], af);
          ab = fmaf((te0+tdb[j])*frcp(d0b), va[j], ab);
          float d1f = fmaf(te1, tdf[j+1], 1.0f);
          float d1b = fmaf(te1, tdb[j+1], 1.0f);
          af = fmaf((te1+tdf[j+1])*frcp(d1f), va[j+1], af);
          ab = fmaf((te1+tdb[j+1])*frcp(d1b), va[j+1], ab);
        }
        #pragma unroll
        for (int off = 1; off < 64; off <<= 1){
          af += __shfl_xor(af, off);
          ab += __shfl_xor(ab, off);
        }
        float ef = __expf(fminf(fmaxf(af - mF, -80.f), 80.f));
        float eb = __expf(fminf(fmaxf(ab - mB, -80.f), 80.f));
        if (lane == 0){ sh.b.ldsE[0][ci][u] = ef; sh.b.ldsE[1][ci][u] = eb; }
      }
      __syncthreads();
      if (tid < 2){
        float s = 0.f;
        for (int ci = 0; ci < 2; ci++)
          for (int u = 0; u < 32; u++) s += sh.b.ldsE[tid][ci][u];
        atomicAdd((float*)(ws+OFF_SUME) + tid*32 + b, s);
      }
      float cf[4] = {0.f,0.f,0.f,0.f}, cb[4] = {0.f,0.f,0.f,0.f};
      if (tid < 384){
        int hf = (tid >= 192) ? 1 : 0;
        int t2 = hf ? tid-192 : tid;
        int i0 = t2*4;
        const u16* E = (const u16*)(ws+OFF_EMB);
        int sbase = hf ? s0B : s0A;
        #pragma unroll 4
        for (int u = 0; u < 32; u++){
          ushort4 x4 = *(const ushort4*)(E + ((size_t)(b*S_ + sbase + u))*I_ + i0);
          float wf = sh.b.ldsE[0][hf][u];
          float wb = sh.b.ldsE[1][1-hf][31-u];   // emb[s] pairs with e_b[S-1-s]
          float x0 = bf2f(x4.x), x1 = bf2f(x4.y), x2 = bf2f(x4.z), x3 = bf2f(x4.w);
          cf[0] = fmaf(wf, x0, cf[0]); cf[1] = fmaf(wf, x1, cf[1]);
          cf[2] = fmaf(wf, x2, cf[2]); cf[3] = fmaf(wf, x3, cf[3]);
          cb[0] = fmaf(wb, x0, cb[0]); cb[1] = fmaf(wb, x1, cb[1]);
          cb[2] = fmaf(wb, x2, cb[2]); cb[3] = fmaf(wb, x3, cb[3]);
        }
        if (hf){
          #pragma unroll
          for (int z = 0; z < 4; z++){
            sh.b.cpart[t2][z]   = cf[z];
            sh.b.cpart[t2][4+z] = cb[z];
          }
        }
      }
      __syncthreads();
      if (tid < 192){
        float* ctx = (float*)(ws+OFF_CTX);
        int i0 = tid*4;
        #pragma unroll
        for (int z = 0; z < 4; z++){
          atomicAdd(&ctx[(size_t)b*I_ + i0 + z],      cf[z] + sh.b.cpart[tid][z]);
          atomicAdd(&ctx[(size_t)(32+b)*I_ + i0 + z], cb[z] + sh.b.cpart[tid][4+z]);
        }
      }
    }
    gridbar(bar, ++gen);
    // ================= phase C: ctx@WihL^T, LSTM cell, out projection =================
    {
      int blk = blockIdx.x;
      int dir = blk >> 7, rest = blk & 127, hc = rest >> 2, qb = rest & 3;
      int rb0 = qb*8;
      const float* se = (const float*)(ws+OFF_SUME) + dir*32;
      if (tid < 8){
        float s_ = se[rb0 + tid];
        sh.c.sum[tid] = s_;
        sh.c.inv[tid] = 1.0f / fmaxf(s_, 1e-30f);
      }
      __syncthreads();
      const float* ctx = (const float*)(ws+OFF_CTX) + (size_t)dir*32*I_;
      for (int idx = tid; idx < 8*I_; idx += NTHR){
        int j = idx / I_, k = idx - j*I_;
        sh.c.Abuf[j][k] = f2bf(ctx[(size_t)(rb0+j)*I_ + k] * sh.c.inv[j]);
      }
      __syncthreads();
      f32x4 acc = {0.f,0.f,0.f,0.f};
      if (wave < 4){
        int gt = wave;
        const u16* Wp = (const u16*)(ws+OFF_WIL) + (size_t)dir*G4H*I_;
        int n_g = gt*512 + hc*16 + lr;
        const u16* bp = Wp + (size_t)n_g*I_ + lkb;
        for (int k = 0; k < I_; k += 32){
          bf16x8 av = *(const bf16x8*)(&sh.c.Abuf[lr][k + lkb]);
          bf16x8 bv = *(const bf16x8*)(bp + k);
          acc = __builtin_amdgcn_mfma_f32_16x16x32_bf16(av, bv, acc, 0, 0, 0);
        }
      } else {
        int gt = wave - 4;
        const float* xW = (const float*)(ws+OFF_XW);
        const float* hW = (const float*)(ws+OFF_HWH);
        const float* bih = dir ? bih_b : bih_f;
        const float* bhh = dir ? bhh_b : bhh_f;
        int j0 = lane >> 4, col = lane & 15;
        int n = gt*512 + hc*16 + col;
        #pragma unroll
        for (int jj = j0; jj < 8; jj += 4){
          size_t rr = (size_t)(dir*32 + rb0 + jj);
          sh.c.Gpre[gt][jj][col] = xW[rr*G4H + n] + hW[rr*G4H + n] + bih[n] + bhh[n];
        }
      }
      __syncthreads();
      if (wave < 4){
        int gt = wave, col = lane & 15;
        #pragma unroll
        for (int q = 0; q < 4; q++){
          int row = row4 + q;
          if (row < 8) sh.c.Gs[gt][row][col] = acc[q] + sh.c.Gpre[gt][row][col];
        }
      }
      __syncthreads();
      float* cS = (float*)(ws+OFF_C);
      u16* hBw = (u16*)(ws+OFF_H);
      if (tid < 128){
        int j = tid >> 4, col = tid & 15;
        int hg = hc*16 + col;
        size_t rr = (size_t)(dir*32 + rb0 + j);
        float ig = sigm(sh.c.Gs[0][j][col]);
        float fg = sigm(sh.c.Gs[1][j][col]);
        float gg = tanhf(sh.c.Gs[2][j][col]);
        float og = sigm(sh.c.Gs[3][j][col]);
        float cn = fmaf(fg, cS[rr*H_ + hg], ig*gg);
        float hn = og * tanhf(cn);
        cS[rr*H_ + hg] = cn;
        hBw[rr*H_ + hg] = f2bf(hn);
        sh.c.Hb[j][col] = hn;
      }
      __syncthreads();
      if (tid < 80){
        int bb = tid/10, cc = tid - bb*10;
        const float* wr = Wout + (size_t)cc*1024 + dir*512 + hc*16;
        float s = 0.f;
        #pragma unroll
        for (int j = 0; j < 16; j++) s = fmaf(sh.c.Hb[bb][j], wr[j], s);
        if (dir == 0 && hc == 0) s += bout[cc];
        int st = dir ? (S_-1-t) : t;
        atomicAdd(&out[((size_t)(qb*8+bb)*S_ + st)*C_ + cc], s);
      }
      if (hc == 0 && tid < 8){
        float* mbp = (float*)(ws+OFF_M);
        mbp[dir*32 + rb0 + tid] += logf(fmaxf(sh.c.sum[tid], 1e-30f));
      }
    }
    gridbar(bar, ++gen);
  }
}

// ---------------- host launcher ----------------
extern "C" void kernel_launch(void* const* d_in, const int* in_sizes, int n_in,
                              void* d_out, int out_size, void* d_ws, size_t ws_size,
                              hipStream_t stream){
  const float* emb   = (const float*)d_in[0];
  const float* Wenc  = (const float*)d_in[1];
  const float* benc  = (const float*)d_in[2];
  const float* Wdec  = (const float*)d_in[3];
  const float* bdec  = (const float*)d_in[4];
  const float* v     = (const float*)d_in[5];
  const float* Wih_f = (const float*)d_in[6];
  const float* Whh_f = (const float*)d_in[7];
  const float* bih_f = (const float*)d_in[8];
  const float* bhh_f = (const float*)d_in[9];
  const float* Wih_b = (const float*)d_in[10];
  const float* Whh_b = (const float*)d_in[11];
  const float* bih_b = (const float*)d_in[12];
  const float* bhh_b = (const float*)d_in[13];
  const float* Wout  = (const float*)d_in[14];
  const float* bout  = (const float*)d_in[15];
  float* out = (float*)d_out;
  char* ws = (char*)d_ws;
  if (ws_size < WS_NEED) return;   // fail loudly via validation

  k_setup<<<dim3(512), dim3(256), 0, stream>>>(ws, Wenc, Wdec, Whh_f, Whh_b, Wih_f, Wih_b, out);
  k_embconv<<<dim3(2048), dim3(256), 0, stream>>>(ws, emb);
  k_enc<<<dim3(8192), dim3(256), 0, stream>>>(ws, benc);
  k_persist<<<dim3(NBLK), dim3(NTHR), 0, stream>>>(ws, bdec, v,
      bih_f, bhh_f, bih_b, bhh_b, Wout, bout, out);
}

// Round 5
// 28558.383 us; speedup vs baseline: 2.1549x; 1.2218x over previous
//
#include <hip/hip_runtime.h>
#include <stdint.h>

#define DEVINL __device__ __forceinline__

constexpr int B_  = 32;
constexpr int S_  = 512;
constexpr int I_  = 768;
constexpr int H_  = 512;
constexpr int C_  = 10;
constexpr int R_  = 64;     // 2 dirs * B_
constexpr int G4H = 2048;   // 4*H_
constexpr int I2_ = 1536;   // 2*I_
constexpr int NBLK = 256;   // persistent grid (1 block/CU co-resident)
constexpr int NTHR = 512;

using bf16x8 = __attribute__((ext_vector_type(8))) short;
using f32x4  = __attribute__((ext_vector_type(4))) float;
typedef unsigned short u16;
typedef unsigned int   u32;

// ---------------- workspace layout (bytes) ----------------
constexpr size_t OFF_TE   = 0;                                   // u16 [B_*S_][H_]  tanh(enc_proj)
constexpr size_t OFF_EMB  = OFF_TE   + (size_t)B_*S_*H_*2;       // u16 [B_*S_][I_]  embeds bf16
constexpr size_t OFF_WDEC = OFF_EMB  + (size_t)B_*S_*I_*2;       // u16 [H_][H_]
constexpr size_t OFF_WHH  = OFF_WDEC + (size_t)H_*H_*2;          // u16 [2][G4H][H_]
constexpr size_t OFF_WIL  = OFF_WHH  + (size_t)2*G4H*H_*2;       // u16 [2][G4H][I_] Wih cols 0..767
constexpr size_t OFF_WIR  = OFF_WIL  + (size_t)2*G4H*I_*2;       // u16 [2][G4H][I_] Wih cols 768..1535
constexpr size_t OFF_WENC = OFF_WIR  + (size_t)2*G4H*I_*2;       // u16 [H_][I_]
constexpr size_t OFF_H    = OFF_WENC + (size_t)H_*I_*2;          // u16 [R_][H_]   h state (bf16)
constexpr size_t OFF_C    = OFF_H    + (size_t)R_*H_*2;          // f32 [R_][H_]   c state
constexpr size_t OFF_TD   = OFF_C    + (size_t)R_*H_*4;          // f32 [R_][H_]   tanh(dec)
constexpr size_t OFF_HWH  = OFF_TD   + (size_t)R_*H_*4;          // f32 [R_][G4H]  h @ Whh^T
constexpr size_t OFF_XW   = OFF_HWH  + (size_t)R_*G4H*4;         // f32 [R_][G4H]  x_t @ WihR^T
constexpr size_t OFF_CTX  = OFF_XW   + (size_t)R_*G4H*4;         // f32 [R_][I_]   unnormalized ctx
constexpr size_t OFF_SUME = OFF_CTX  + (size_t)R_*I_*4;          // f32 [R_]
constexpr size_t OFF_M    = OFF_SUME + 256;                      // f32 [R_] running logsumexp shift
// barrier: u32 words. [0..31] root line; [32..63] generation line;
// [64 + g*32] group-g counter line (g = 0..31). All monotonic, zeroed per launch.
constexpr size_t OFF_BAR  = OFF_M    + 256;
constexpr int    BAR_W    = 64 + 32*32;                          // 1088 u32 words
constexpr size_t WS_NEED  = OFF_BAR + BAR_W*4;

// ---------------- helpers ----------------
DEVINL float asf(u32 u){ union{u32 i; float f;} x; x.i=u; return x.f; }
DEVINL u32   asu(float f){ union{u32 i; float f;} x; x.f=f; return x.i; }
DEVINL float bf2f(u16 h){ return asf((u32)h << 16); }
DEVINL u16   f2bf(float f){ u32 u = asu(f); return (u16)((u + 0x7fffu + ((u>>16)&1u)) >> 16); }
DEVINL float frcp(float x){
#if __has_builtin(__builtin_amdgcn_rcpf)
  return __builtin_amdgcn_rcpf(x);
#else
  return 1.0f/x;
#endif
}
DEVINL float sigm(float x){ return frcp(1.0f + __expf(-x)); }

// grid barrier, 2-level tree with monotonic targets (n = 1-based barrier idx):
//   group g (8 blocks, own cacheline): fetch_add; last (old == 8n-1) bumps root.
//   root (32 arrivals): last (old == 32n-1) publishes generation = n.
//   everyone spins on the generation word (read-only hot line, cheap).
DEVINL void gridbar(u32* bar, u32 n){
  __syncthreads();
  if (threadIdx.x == 0){
    __threadfence();   // release this block's phase writes
    u32 g = blockIdx.x >> 3;
    u32 old = __hip_atomic_fetch_add(&bar[64 + g*32], 1u, __ATOMIC_RELAXED, __HIP_MEMORY_SCOPE_AGENT);
    if (old == n*8u - 1u){
      u32 r = __hip_atomic_fetch_add(&bar[0], 1u, __ATOMIC_RELAXED, __HIP_MEMORY_SCOPE_AGENT);
      if (r == n*32u - 1u){
        __hip_atomic_store(&bar[32], n, __ATOMIC_RELAXED, __HIP_MEMORY_SCOPE_AGENT);
      }
    }
    while (__hip_atomic_load(&bar[32], __ATOMIC_RELAXED, __HIP_MEMORY_SCOPE_AGENT) < n)
      __builtin_amdgcn_s_sleep(2);
    __threadfence();   // acquire side
  }
  __syncthreads();
}

// ---------------- shared-memory union ----------------
struct SMemB { float ldsE[2][2][32]; float cpart[192][8]; };
struct SMemC { u16 Abuf[16][776]; float Gpre[4][8][16]; float Gs[4][8][16];
               float Hb[8][16]; float inv[8]; float sum[8]; };
union alignas(16) SMem { SMemB b; SMemC c; };

// ---------------- one-time setup: zero state, convert weights ----------------
__global__ void k_setup(char* ws, const float* Wenc, const float* Wdec,
                        const float* Whh_f, const float* Whh_b,
                        const float* Wih_f, const float* Wih_b,
                        float* out){
  int tid = blockIdx.x*blockDim.x + threadIdx.x;
  int nth = gridDim.x*blockDim.x;
  for (int i = tid; i < B_*S_*C_; i += nth) out[i] = 0.f;
  u16* hB = (u16*)(ws+OFF_H);
  for (int i = tid; i < R_*H_; i += nth) hB[i] = 0;
  float* cS = (float*)(ws+OFF_C);
  for (int i = tid; i < R_*H_; i += nth) cS[i] = 0.f;
  float* mb = (float*)(ws+OFF_M);
  for (int i = tid; i < R_; i += nth) mb[i] = 0.f;
  u32* bar = (u32*)(ws+OFF_BAR);
  for (int i = tid; i < BAR_W; i += nth) bar[i] = 0u;
  u16* wd = (u16*)(ws+OFF_WDEC);
  for (int i = tid; i < H_*H_; i += nth) wd[i] = f2bf(Wdec[i]);
  u16* we = (u16*)(ws+OFF_WENC);
  for (int i = tid; i < H_*I_; i += nth) we[i] = f2bf(Wenc[i]);
  u16* wh = (u16*)(ws+OFF_WHH);
  for (int i = tid; i < G4H*H_; i += nth){
    wh[i] = f2bf(Whh_f[i]);
    wh[G4H*H_ + i] = f2bf(Whh_b[i]);
  }
  u16* wl = (u16*)(ws+OFF_WIL);
  u16* wr = (u16*)(ws+OFF_WIR);
  for (int i = tid; i < G4H*I_; i += nth){
    int n = i / I_, k = i - n*I_;
    wl[i]            = f2bf(Wih_f[n*I2_ + k]);
    wr[i]            = f2bf(Wih_f[n*I2_ + I_ + k]);
    wl[G4H*I_ + i]   = f2bf(Wih_b[n*I2_ + k]);
    wr[G4H*I_ + i]   = f2bf(Wih_b[n*I2_ + I_ + k]);
  }
}

// ---------------- one-time: embeds -> bf16 ----------------
__global__ void k_embconv(char* ws, const float* emb){
  u16* e = (u16*)(ws+OFF_EMB);
  int tid = blockIdx.x*blockDim.x + threadIdx.x;
  int nth = gridDim.x*blockDim.x;
  int n4 = (B_*S_*I_)/4;
  const float4* src = (const float4*)emb;
  ushort4* dst = (ushort4*)e;
  for (int i = tid; i < n4; i += nth){
    float4 x = src[i];
    ushort4 o;
    o.x = f2bf(x.x); o.y = f2bf(x.y); o.z = f2bf(x.z); o.w = f2bf(x.w);
    dst[i] = o;
  }
}

// ---------------- one-time: Te = tanh(embB @ WencB^T + benc) ----------------
__global__ __launch_bounds__(256) void k_enc(char* ws, const float* benc){
  const u16* A = (const u16*)(ws+OFF_EMB);
  const u16* W = (const u16*)(ws+OFF_WENC);
  u16* Te = (u16*)(ws+OFF_TE);
  int wg = blockIdx.x;
  int mt = wg >> 3, ng = wg & 7;
  int wave = threadIdx.x >> 6, lane = threadIdx.x & 63;
  int m0 = mt*16, n0 = ng*64 + wave*16;
  int lr = lane & 15, lkb = (lane>>4)*8;
  const u16* ap = A + (size_t)(m0+lr)*I_ + lkb;
  const u16* bp = W + (size_t)(n0+lr)*I_ + lkb;
  f32x4 acc = {0.f,0.f,0.f,0.f};
  for (int k = 0; k < I_; k += 32){
    bf16x8 a = *(const bf16x8*)(ap + k);
    bf16x8 b = *(const bf16x8*)(bp + k);
    acc = __builtin_amdgcn_mfma_f32_16x16x32_bf16(a, b, acc, 0, 0, 0);
  }
  int row4 = (lane>>4)*4;
  #pragma unroll
  for (int q = 0; q < 4; q++){
    int rr = m0 + row4 + q, cc = n0 + lr;
    Te[(size_t)rr*H_ + cc] = f2bf(tanhf(acc[q] + benc[cc]));
  }
}

// ---------------- persistent stepper: 512 steps, 3 grid barriers/step ----------------
// LDS: 98304 (embLds, persistent attention slice) + 29696 (phase union) = 128000 B
// -> 1 block/CU. Te slice lives in 32 VGPRs/thread (teR[8], fully unrolled).
__global__ __launch_bounds__(NTHR) void k_persist(char* ws,
        const float* bdec, const float* v,
        const float* bih_f, const float* bhh_f,
        const float* bih_b, const float* bhh_b,
        const float* Wout, const float* bout, float* out){
  __shared__ SMem sh;
  __shared__ u16 embLds[64][I_];   // rows 0..31: s0A+u ; rows 32..63: s0B+u
  u32* bar = (u32*)(ws+OFF_BAR);
  u32 gen = 0;
  const int tid = threadIdx.x, lane = tid & 63, wave = tid >> 6;
  const int lr = lane & 15, lkb = (lane>>4)*8, row4 = (lane>>4)*4;

  // attention slice geometry (fixed for the whole sequence)
  const int ab   = blockIdx.x & 31;        // batch
  const int pair = blockIdx.x >> 5;        // 0..7
  const int s0A  = pair*32, s0B = S_ - pair*32 - 32;
  const int h0   = lane*8;

  // zero Abuf once; rows 8..15 are never clobbered by phase B (its struct
  // spans only the first 6656 bytes) and rows 0..7 are rewritten every step,
  // so this establishes permanent zero-padding rows.
  for (int i = tid; i < 16*776; i += NTHR) ((u16*)sh.c.Abuf)[i] = 0;

  // cache EMB slice (98 KB) into LDS once
  {
    const u16* E = (const u16*)(ws+OFF_EMB);
    for (int idx = tid; idx < 64*(I_/8); idx += NTHR){
      int r = idx / (I_/8), c8 = idx - r*(I_/8);
      int s = (r < 32) ? (s0A + r) : (s0B + (r-32));
      *(uint4*)(&embLds[r][c8*8]) = *(const uint4*)(E + ((size_t)(ab*S_ + s))*I_ + c8*8);
    }
  }
  // cache Te slice into registers: row r = wave+8k, 8 bf16 at h0 per lane
  bf16x8 teR[8];
  {
    const u16* Te = (const u16*)(ws+OFF_TE);
    #pragma unroll
    for (int k = 0; k < 8; ++k){
      int r = wave + 8*k;
      int ci = r >> 5, u = r & 31;
      int s = (ci ? s0B : s0A) + u;
      teR[k] = *(const bf16x8*)(Te + ((size_t)(ab*S_ + s))*H_ + h0);
    }
  }
  __syncthreads();

  for (int t = 0; t < S_; ++t){
    // ================= phase A: dec/Td, h@Whh^T, x_t@WihR^T; zero ctx/sumE =================
    {
      int gw = blockIdx.x*8 + wave;     // 0..2047
      const u16* hB = (const u16*)(ws+OFF_H);
      if (gw < 128){                    // dec: M=64, N=512, K=512
        int m0 = (gw>>5)*16, n0 = (gw&31)*16;
        const u16* W = (const u16*)(ws+OFF_WDEC);
        const u16* ap = hB + (size_t)(m0+lr)*H_ + lkb;
        const u16* bp = W + (size_t)(n0+lr)*H_ + lkb;
        f32x4 acc = {0.f,0.f,0.f,0.f};
        for (int k = 0; k < H_; k += 32){
          bf16x8 a = *(const bf16x8*)(ap + k);
          bf16x8 b = *(const bf16x8*)(bp + k);
          acc = __builtin_amdgcn_mfma_f32_16x16x32_bf16(a, b, acc, 0, 0, 0);
        }
        float* Td = (float*)(ws+OFF_TD);
        #pragma unroll
        for (int q = 0; q < 4; q++){
          int rr = m0 + row4 + q, cc = n0 + lr;
          Td[rr*H_ + cc] = tanhf(acc[q] + bdec[cc]);
        }
      } else if (gw < 640){             // hWhh: per dir M=32, N=2048, K=512
        int t2 = gw - 128; int dir = t2 >> 8; int t3 = t2 & 255;
        int m0 = dir*32 + (t3>>7)*16;
        int n0 = (t3 & 127)*16;
        const u16* W = (const u16*)(ws+OFF_WHH) + (size_t)dir*G4H*H_;
        const u16* ap = hB + (size_t)(m0+lr)*H_ + lkb;
        const u16* bp = W + (size_t)(n0+lr)*H_ + lkb;
        f32x4 acc = {0.f,0.f,0.f,0.f};
        for (int k = 0; k < H_; k += 32){
          bf16x8 a = *(const bf16x8*)(ap + k);
          bf16x8 b = *(const bf16x8*)(bp + k);
          acc = __builtin_amdgcn_mfma_f32_16x16x32_bf16(a, b, acc, 0, 0, 0);
        }
        float* o = (float*)(ws+OFF_HWH);
        #pragma unroll
        for (int q = 0; q < 4; q++){
          int rr = m0 + row4 + q;
          o[(size_t)rr*G4H + n0 + lr] = acc[q];
        }
      } else if (gw < 1152){            // xW: per dir M=32, N=2048, K=768
        int t2 = gw - 640; int dir = t2 >> 8; int t3 = t2 & 255;
        int bbase = (t3>>7)*16;
        int n0 = (t3 & 127)*16;
        int trow = dir ? (S_-1-t) : t;
        const u16* E = (const u16*)(ws+OFF_EMB);
        const u16* W = (const u16*)(ws+OFF_WIR) + (size_t)dir*G4H*I_;
        const u16* ap = E + ((size_t)(bbase+lr)*S_ + trow)*I_ + lkb;
        const u16* bp = W + (size_t)(n0+lr)*I_ + lkb;
        f32x4 acc = {0.f,0.f,0.f,0.f};
        for (int k = 0; k < I_; k += 32){
          bf16x8 a = *(const bf16x8*)(ap + k);
          bf16x8 b = *(const bf16x8*)(bp + k);
          acc = __builtin_amdgcn_mfma_f32_16x16x32_bf16(a, b, acc, 0, 0, 0);
        }
        float* o = (float*)(ws+OFF_XW);
        #pragma unroll
        for (int q = 0; q < 4; q++){
          int bb = bbase + row4 + q;
          o[(size_t)(dir*32+bb)*G4H + n0 + lr] = acc[q];
        }
      } else {                          // zero ctx & sumE for this step
        int zid = (gw - 1152)*64 + lane;      // covers 49152+64
        float* ctx = (float*)(ws+OFF_CTX);
        if (zid < R_*I_) ctx[zid] = 0.f;
        if (zid < R_) ((float*)(ws+OFF_SUME))[zid] = 0.f;
      }
    }
    gridbar(bar, ++gen);
    // ================= phase B: scores via tanh-identity, exp, ctx partials =================
    {
      const float* Td = (const float*)(ws+OFF_TD);
      const float* mbp = (const float*)(ws+OFF_M);
      float tdf[8], tdb[8], va[8];
      #pragma unroll
      for (int j = 0; j < 8; j++){
        tdf[j] = Td[ab*H_ + h0 + j];
        tdb[j] = Td[(32+ab)*H_ + h0 + j];
        va[j]  = v[h0 + j];
      }
      float mF = mbp[ab], mB = mbp[32+ab];
      #pragma unroll
      for (int k = 0; k < 8; ++k){
        int r = wave + 8*k;
        int ci = r >> 5, u = r & 31;
        bf16x8 tv = teR[k];
        float af = 0.f, ab2 = 0.f;
        #pragma unroll
        for (int j = 0; j < 8; ++j){
          float te = bf2f((u16)tv[j]);
          float df = fmaf(te, tdf[j], 1.0f);
          float db = fmaf(te, tdb[j], 1.0f);
          af  = fmaf((te+tdf[j])*frcp(df), va[j], af);
          ab2 = fmaf((te+tdb[j])*frcp(db), va[j], ab2);
        }
        #pragma unroll
        for (int off = 1; off < 64; off <<= 1){
          af  += __shfl_xor(af, off);
          ab2 += __shfl_xor(ab2, off);
        }
        float ef = __expf(fminf(fmaxf(af  - mF, -80.f), 80.f));
        float eb = __expf(fminf(fmaxf(ab2 - mB, -80.f), 80.f));
        if (lane == 0){ sh.b.ldsE[0][ci][u] = ef; sh.b.ldsE[1][ci][u] = eb; }
      }
      __syncthreads();
      if (tid < 2){
        float s = 0.f;
        for (int ci = 0; ci < 2; ci++)
          for (int u = 0; u < 32; u++) s += sh.b.ldsE[tid][ci][u];
        atomicAdd((float*)(ws+OFF_SUME) + tid*32 + ab, s);
      }
      float cf[4] = {0.f,0.f,0.f,0.f}, cb[4] = {0.f,0.f,0.f,0.f};
      if (tid < 384){
        int hf = (tid >= 192) ? 1 : 0;
        int t2 = hf ? tid-192 : tid;
        int i0 = t2*4;
        #pragma unroll 4
        for (int u = 0; u < 32; u++){
          ushort4 x4 = *(const ushort4*)(&embLds[hf*32 + u][i0]);
          float wf = sh.b.ldsE[0][hf][u];
          float wb = sh.b.ldsE[1][1-hf][31-u];   // emb[s] pairs with e_b[S-1-s]
          float x0 = bf2f(x4.x), x1 = bf2f(x4.y), x2 = bf2f(x4.z), x3 = bf2f(x4.w);
          cf[0] = fmaf(wf, x0, cf[0]); cf[1] = fmaf(wf, x1, cf[1]);
          cf[2] = fmaf(wf, x2, cf[2]); cf[3] = fmaf(wf, x3, cf[3]);
          cb[0] = fmaf(wb, x0, cb[0]); cb[1] = fmaf(wb, x1, cb[1]);
          cb[2] = fmaf(wb, x2, cb[2]); cb[3] = fmaf(wb, x3, cb[3]);
        }
        if (hf){
          #pragma unroll
          for (int z = 0; z < 4; z++){
            sh.b.cpart[t2][z]   = cf[z];
            sh.b.cpart[t2][4+z] = cb[z];
          }
        }
      }
      __syncthreads();
      if (tid < 192){
        float* ctx = (float*)(ws+OFF_CTX);
        int i0 = tid*4;
        #pragma unroll
        for (int z = 0; z < 4; z++){
          atomicAdd(&ctx[(size_t)ab*I_ + i0 + z],      cf[z] + sh.b.cpart[tid][z]);
          atomicAdd(&ctx[(size_t)(32+ab)*I_ + i0 + z], cb[z] + sh.b.cpart[tid][4+z]);
        }
      }
    }
    gridbar(bar, ++gen);
    // ================= phase C: ctx@WihL^T, LSTM cell, out projection =================
    {
      int blk = blockIdx.x;
      int dir = blk >> 7, rest = blk & 127, hc = rest >> 2, qb = rest & 3;
      int rb0 = qb*8;
      const float* se = (const float*)(ws+OFF_SUME) + dir*32;
      if (tid < 8){
        float s_ = se[rb0 + tid];
        sh.c.sum[tid] = s_;
        sh.c.inv[tid] = 1.0f / fmaxf(s_, 1e-30f);
      }
      __syncthreads();
      const float* ctx = (const float*)(ws+OFF_CTX) + (size_t)dir*32*I_;
      for (int idx = tid; idx < 8*I_; idx += NTHR){
        int j = idx / I_, k = idx - j*I_;
        sh.c.Abuf[j][k] = f2bf(ctx[(size_t)(rb0+j)*I_ + k] * sh.c.inv[j]);
      }
      __syncthreads();
      f32x4 acc = {0.f,0.f,0.f,0.f};
      if (wave < 4){
        int gt = wave;
        const u16* Wp = (const u16*)(ws+OFF_WIL) + (size_t)dir*G4H*I_;
        int n_g = gt*512 + hc*16 + lr;
        const u16* bp = Wp + (size_t)n_g*I_ + lkb;
        for (int k = 0; k < I_; k += 32){
          bf16x8 av = *(const bf16x8*)(&sh.c.Abuf[lr][k + lkb]);
          bf16x8 bv = *(const bf16x8*)(bp + k);
          acc = __builtin_amdgcn_mfma_f32_16x16x32_bf16(av, bv, acc, 0, 0, 0);
        }
      } else {
        int gt = wave - 4;
        const float* xW = (const float*)(ws+OFF_XW);
        const float* hW = (const float*)(ws+OFF_HWH);
        const float* bih = dir ? bih_b : bih_f;
        const float* bhh = dir ? bhh_b : bhh_f;
        int j0 = lane >> 4, col = lane & 15;
        int n = gt*512 + hc*16 + col;
        #pragma unroll
        for (int jj = j0; jj < 8; jj += 4){
          size_t rr = (size_t)(dir*32 + rb0 + jj);
          sh.c.Gpre[gt][jj][col] = xW[rr*G4H + n] + hW[rr*G4H + n] + bih[n] + bhh[n];
        }
      }
      __syncthreads();
      if (wave < 4){
        int gt = wave, col = lane & 15;
        #pragma unroll
        for (int q = 0; q < 4; q++){
          int row = row4 + q;
          if (row < 8) sh.c.Gs[gt][row][col] = acc[q] + sh.c.Gpre[gt][row][col];
        }
      }
      __syncthreads();
      float* cS = (float*)(ws+OFF_C);
      u16* hBw = (u16*)(ws+OFF_H);
      if (tid < 128){
        int j = tid >> 4, col = tid & 15;
        int hg = hc*16 + col;
        size_t rr = (size_t)(dir*32 + rb0 + j);
        float ig = sigm(sh.c.Gs[0][j][col]);
        float fg = sigm(sh.c.Gs[1][j][col]);
        float gg = tanhf(sh.c.Gs[2][j][col]);
        float og = sigm(sh.c.Gs[3][j][col]);
        float cn = fmaf(fg, cS[rr*H_ + hg], ig*gg);
        float hn = og * tanhf(cn);
        cS[rr*H_ + hg] = cn;
        hBw[rr*H_ + hg] = f2bf(hn);
        sh.c.Hb[j][col] = hn;
      }
      __syncthreads();
      if (tid < 80){
        int bb = tid/10, cc = tid - bb*10;
        const float* wr = Wout + (size_t)cc*1024 + dir*512 + hc*16;
        float s = 0.f;
        #pragma unroll
        for (int j = 0; j < 16; j++) s = fmaf(sh.c.Hb[bb][j], wr[j], s);
        if (dir == 0 && hc == 0) s += bout[cc];
        int st = dir ? (S_-1-t) : t;
        atomicAdd(&out[((size_t)(qb*8+bb)*S_ + st)*C_ + cc], s);
      }
      if (hc == 0 && tid < 8){
        float* mbp = (float*)(ws+OFF_M);
        mbp[dir*32 + rb0 + tid] += logf(fmaxf(sh.c.sum[tid], 1e-30f));
      }
    }
    gridbar(bar, ++gen);
  }
}

// ---------------- host launcher ----------------
extern "C" void kernel_launch(void* const* d_in, const int* in_sizes, int n_in,
                              void* d_out, int out_size, void* d_ws, size_t ws_size,
                              hipStream_t stream){
  const float* emb   = (const float*)d_in[0];
  const float* Wenc  = (const float*)d_in[1];
  const float* benc  = (const float*)d_in[2];
  const float* Wdec  = (const float*)d_in[3];
  const float* bdec  = (const float*)d_in[4];
  const float* v     = (const float*)d_in[5];
  const float* Wih_f = (const float*)d_in[6];
  const float* Whh_f = (const float*)d_in[7];
  const float* bih_f = (const float*)d_in[8];
  const float* bhh_f = (const float*)d_in[9];
  const float* Wih_b = (const float*)d_in[10];
  const float* Whh_b = (const float*)d_in[11];
  const float* bih_b = (const float*)d_in[12];
  const float* bhh_b = (const float*)d_in[13];
  const float* Wout  = (const float*)d_in[14];
  const float* bout  = (const float*)d_in[15];
  float* out = (float*)d_out;
  char* ws = (char*)d_ws;
  if (ws_size < WS_NEED) return;   // fail loudly via validation

  k_setup<<<dim3(512), dim3(256), 0, stream>>>(ws, Wenc, Wdec, Whh_f, Whh_b, Wih_f, Wih_b, out);
  k_embconv<<<dim3(2048), dim3(256), 0, stream>>>(ws, emb);
  k_enc<<<dim3(8192), dim3(256), 0, stream>>>(ws, benc);
  k_persist<<<dim3(NBLK), dim3(NTHR), 0, stream>>>(ws, bdec, v,
      bih_f, bhh_f, bih_b, bhh_b, Wout, bout, out);
}

// Round 6
// 27481.693 us; speedup vs baseline: 2.2394x; 1.0392x over previous
//
#include <hip/hip_runtime.h>
#include <stdint.h>

#define DEVINL __device__ __forceinline__

constexpr int B_  = 32;
constexpr int S_  = 512;
constexpr int I_  = 768;
constexpr int H_  = 512;
constexpr int C_  = 10;
constexpr int R_  = 64;     // 2 dirs * B_
constexpr int G4H = 2048;   // 4*H_
constexpr int I2_ = 1536;   // 2*I_
constexpr int NBLK = 256;   // persistent grid (1 block/CU co-resident)
constexpr int NTHR = 512;

using bf16x8 = __attribute__((ext_vector_type(8))) short;
using f32x4  = __attribute__((ext_vector_type(4))) float;
typedef unsigned short u16;
typedef unsigned int   u32;

// ---------------- workspace layout (bytes) ----------------
constexpr size_t OFF_TE   = 0;                                   // u16 [B_*S_][H_]  tanh(enc_proj)
constexpr size_t OFF_EMB  = OFF_TE   + (size_t)B_*S_*H_*2;       // u16 [B_*S_][I_]  embeds bf16
constexpr size_t OFF_WDEC = OFF_EMB  + (size_t)B_*S_*I_*2;       // u16 [H_][H_]
constexpr size_t OFF_WHH  = OFF_WDEC + (size_t)H_*H_*2;          // u16 [2][G4H][H_]
constexpr size_t OFF_WIL  = OFF_WHH  + (size_t)2*G4H*H_*2;       // u16 [2][G4H][I_] Wih cols 0..767
constexpr size_t OFF_WIR  = OFF_WIL  + (size_t)2*G4H*I_*2;       // u16 [2][G4H][I_] Wih cols 768..1535
constexpr size_t OFF_WENC = OFF_WIR  + (size_t)2*G4H*I_*2;       // u16 [H_][I_]
constexpr size_t OFF_H    = OFF_WENC + (size_t)H_*I_*2;          // u16 [R_][H_]   h state (bf16)
constexpr size_t OFF_C    = OFF_H    + (size_t)R_*H_*2;          // f32 [R_][H_]   c state
constexpr size_t OFF_TD   = OFF_C    + (size_t)R_*H_*4;          // f32 [R_][H_]   tanh(dec)
constexpr size_t OFF_HWH  = OFF_TD   + (size_t)R_*H_*4;          // f32 [R_][G4H]  h @ Whh^T
constexpr size_t OFF_XW   = OFF_HWH  + (size_t)R_*G4H*4;         // f32 [R_][G4H]  x_t @ WihR^T
constexpr size_t OFF_CTX  = OFF_XW   + (size_t)R_*G4H*4;         // f32 [R_][I_]   unnormalized ctx
constexpr size_t OFF_SUME = OFF_CTX  + (size_t)R_*I_*4;          // f32 [R_]
constexpr size_t OFF_M    = OFF_SUME + 256;                      // f32 [R_] running logsumexp shift
// barrier: u32 words. [0..31] root line; [32..63] generation line;
// [64 + g*32] group-g counter line (g = 0..31). All monotonic, zeroed per launch.
constexpr size_t OFF_BAR  = OFF_M    + 256;
constexpr int    BAR_W    = 64 + 32*32;                          // 1088 u32 words
constexpr size_t WS_NEED  = OFF_BAR + BAR_W*4;

// ---------------- helpers ----------------
DEVINL float asf(u32 u){ union{u32 i; float f;} x; x.i=u; return x.f; }
DEVINL u32   asu(float f){ union{u32 i; float f;} x; x.f=f; return x.i; }
DEVINL float bf2f(u16 h){ return asf((u32)h << 16); }
DEVINL u16   f2bf(float f){ u32 u = asu(f); return (u16)((u + 0x7fffu + ((u>>16)&1u)) >> 16); }
DEVINL float frcp(float x){
#if __has_builtin(__builtin_amdgcn_rcpf)
  return __builtin_amdgcn_rcpf(x);
#else
  return 1.0f/x;
#endif
}
DEVINL float sigm(float x){ return frcp(1.0f + __expf(-x)); }

// grid barrier, 2-level tree with monotonic targets (validated R4/R5)
DEVINL void gridbar(u32* bar, u32 n){
  __syncthreads();
  if (threadIdx.x == 0){
    __threadfence();   // release this block's phase writes
    u32 g = blockIdx.x >> 3;
    u32 old = __hip_atomic_fetch_add(&bar[64 + g*32], 1u, __ATOMIC_RELAXED, __HIP_MEMORY_SCOPE_AGENT);
    if (old == n*8u - 1u){
      u32 r = __hip_atomic_fetch_add(&bar[0], 1u, __ATOMIC_RELAXED, __HIP_MEMORY_SCOPE_AGENT);
      if (r == n*32u - 1u){
        __hip_atomic_store(&bar[32], n, __ATOMIC_RELAXED, __HIP_MEMORY_SCOPE_AGENT);
      }
    }
    while (__hip_atomic_load(&bar[32], __ATOMIC_RELAXED, __HIP_MEMORY_SCOPE_AGENT) < n)
      __builtin_amdgcn_s_sleep(2);
    __threadfence();   // acquire side
  }
  __syncthreads();
}

// ---------------- shared-memory union (phase-transient) ----------------
struct SMemB { float ldsE[2][2][32]; float cpart[4][96][16]; };           // 25088 B
struct SMemC { u16 Abuf[16][776]; float Gpre[32][16]; float Gs[32][16];
               float Hb[16][8]; float inv[16]; float sum[16]; };          // 29568 B
union alignas(16) SMem { SMemB b; SMemC c; };

// ---------------- one-time setup: zero state, convert weights ----------------
__global__ void k_setup(char* ws, const float* Wenc, const float* Wdec,
                        const float* Whh_f, const float* Whh_b,
                        const float* Wih_f, const float* Wih_b,
                        float* out){
  int tid = blockIdx.x*blockDim.x + threadIdx.x;
  int nth = gridDim.x*blockDim.x;
  for (int i = tid; i < B_*S_*C_; i += nth) out[i] = 0.f;
  u16* hB = (u16*)(ws+OFF_H);
  for (int i = tid; i < R_*H_; i += nth) hB[i] = 0;
  float* cS = (float*)(ws+OFF_C);
  for (int i = tid; i < R_*H_; i += nth) cS[i] = 0.f;
  float* mb = (float*)(ws+OFF_M);
  for (int i = tid; i < R_; i += nth) mb[i] = 0.f;
  u32* bar = (u32*)(ws+OFF_BAR);
  for (int i = tid; i < BAR_W; i += nth) bar[i] = 0u;
  u16* wd = (u16*)(ws+OFF_WDEC);
  for (int i = tid; i < H_*H_; i += nth) wd[i] = f2bf(Wdec[i]);
  u16* we = (u16*)(ws+OFF_WENC);
  for (int i = tid; i < H_*I_; i += nth) we[i] = f2bf(Wenc[i]);
  u16* wh = (u16*)(ws+OFF_WHH);
  for (int i = tid; i < G4H*H_; i += nth){
    wh[i] = f2bf(Whh_f[i]);
    wh[G4H*H_ + i] = f2bf(Whh_b[i]);
  }
  u16* wl = (u16*)(ws+OFF_WIL);
  u16* wr = (u16*)(ws+OFF_WIR);
  for (int i = tid; i < G4H*I_; i += nth){
    int n = i / I_, k = i - n*I_;
    wl[i]            = f2bf(Wih_f[n*I2_ + k]);
    wr[i]            = f2bf(Wih_f[n*I2_ + I_ + k]);
    wl[G4H*I_ + i]   = f2bf(Wih_b[n*I2_ + k]);
    wr[G4H*I_ + i]   = f2bf(Wih_b[n*I2_ + I_ + k]);
  }
}

// ---------------- one-time: embeds -> bf16 ----------------
__global__ void k_embconv(char* ws, const float* emb){
  u16* e = (u16*)(ws+OFF_EMB);
  int tid = blockIdx.x*blockDim.x + threadIdx.x;
  int nth = gridDim.x*blockDim.x;
  int n4 = (B_*S_*I_)/4;
  const float4* src = (const float4*)emb;
  ushort4* dst = (ushort4*)e;
  for (int i = tid; i < n4; i += nth){
    float4 x = src[i];
    ushort4 o;
    o.x = f2bf(x.x); o.y = f2bf(x.y); o.z = f2bf(x.z); o.w = f2bf(x.w);
    dst[i] = o;
  }
}

// ---------------- one-time: Te = tanh(embB @ WencB^T + benc) ----------------
__global__ __launch_bounds__(256) void k_enc(char* ws, const float* benc){
  const u16* A = (const u16*)(ws+OFF_EMB);
  const u16* W = (const u16*)(ws+OFF_WENC);
  u16* Te = (u16*)(ws+OFF_TE);
  int wg = blockIdx.x;
  int mt = wg >> 3, ng = wg & 7;
  int wave = threadIdx.x >> 6, lane = threadIdx.x & 63;
  int m0 = mt*16, n0 = ng*64 + wave*16;
  int lr = lane & 15, lkb = (lane>>4)*8;
  const u16* ap = A + (size_t)(m0+lr)*I_ + lkb;
  const u16* bp = W + (size_t)(n0+lr)*I_ + lkb;
  f32x4 acc = {0.f,0.f,0.f,0.f};
  for (int k = 0; k < I_; k += 32){
    bf16x8 a = *(const bf16x8*)(ap + k);
    bf16x8 b = *(const bf16x8*)(bp + k);
    acc = __builtin_amdgcn_mfma_f32_16x16x32_bf16(a, b, acc, 0, 0, 0);
  }
  int row4 = (lane>>4)*4;
  #pragma unroll
  for (int q = 0; q < 4; q++){
    int rr = m0 + row4 + q, cc = n0 + lr;
    Te[(size_t)rr*H_ + cc] = f2bf(tanhf(acc[q] + benc[cc]));
  }
}

// ---------------- persistent stepper: weight-stationary, 3 barriers/step ----------------
// LDS: wWhh 16640 + wWIR 24832 + wDec 16640 + wWIL 49664 + wOutL/bsum 448
//      + sh union 29568 = 137792 B -> 1 block/CU. All weight panels pinned
//      for the whole sequence (fence-proof); EMB slice in 64 VGPRs, Te in 32.
__global__ __launch_bounds__(NTHR) void k_persist(char* ws,
        const float* bdec, const float* v,
        const float* bih_f, const float* bhh_f,
        const float* bih_b, const float* bhh_b,
        const float* Wout, const float* bout, float* out){
  __shared__ SMem sh;
  __shared__ alignas(16) u16 wWhh[16][520];   // (dirA,n0A): Whh rows n0A*16..+15
  __shared__ alignas(16) u16 wWIR[16][776];   // (dirA,n0A): WihR rows n0A*16..+15
  __shared__ alignas(16) u16 wDec[16][520];   // blk<32: Wdec rows blk*16..+15
  __shared__ alignas(16) u16 wWIL[32][776];   // (dirC,ncC): packed [g*8+j] = WihL row g*512+ncC*8+j
  __shared__ float wOutL[10][8];
  __shared__ float bsumL[32];
  u32* bar = (u32*)(ws+OFF_BAR);
  u32 gen = 0;
  const int tid = threadIdx.x, lane = tid & 63, wave = tid >> 6;
  const int lr = lane & 15, lkb = (lane>>4)*8, row4 = (lane>>4)*4;
  const int blk = blockIdx.x;
  // phase A keys
  const int dirA = blk & 1, n0A = blk >> 1;
  // phase B keys (attention slice, fixed for whole sequence)
  const int ab   = blk & 31, pair = blk >> 5;
  const int s0A  = pair*32, s0B = S_ - pair*32 - 32;
  const int h0   = lane*8;
  const int cg   = (tid < 384) ? (tid % 96) : 0;   // 8-col group
  const int rq   = (tid < 384) ? (tid / 96) : 0;   // 16-row group
  // phase C keys
  const int dirC = blk >> 7, ncC = (blk >> 1) & 63, qbC = blk & 1;

  // ---- prologue: pin weights into LDS ----
  { const u16* src = (const u16*)(ws+OFF_WHH) + (size_t)dirA*G4H*H_ + (size_t)n0A*16*H_;
    for (int idx = tid; idx < 16*64; idx += NTHR){ int r = idx>>6, c8 = idx&63;
      *(uint4*)&wWhh[r][c8*8] = *(const uint4*)(src + (size_t)r*H_ + c8*8); } }
  { const u16* src = (const u16*)(ws+OFF_WIR) + (size_t)dirA*G4H*I_ + (size_t)n0A*16*I_;
    for (int idx = tid; idx < 16*96; idx += NTHR){ int r = idx/96, c8 = idx - r*96;
      *(uint4*)&wWIR[r][c8*8] = *(const uint4*)(src + (size_t)r*I_ + c8*8); } }
  if (blk < 32){
    const u16* src = (const u16*)(ws+OFF_WDEC) + (size_t)blk*16*H_;
    for (int idx = tid; idx < 16*64; idx += NTHR){ int r = idx>>6, c8 = idx&63;
      *(uint4*)&wDec[r][c8*8] = *(const uint4*)(src + (size_t)r*H_ + c8*8); } }
  { const u16* src = (const u16*)(ws+OFF_WIL) + (size_t)dirC*G4H*I_;
    for (int idx = tid; idx < 32*96; idx += NTHR){ int pr = idx/96, c8 = idx - pr*96;
      int g = pr>>3, j = pr&7;
      *(uint4*)&wWIL[pr][c8*8] = *(const uint4*)(src + (size_t)(g*512 + ncC*8 + j)*I_ + c8*8); } }
  { const float* bihp = dirC ? bih_b : bih_f;
    const float* bhhp = dirC ? bhh_b : bhh_f;
    if (tid < 32){ int g = tid>>3, c = tid&7; int n = g*512 + ncC*8 + c;
      bsumL[tid] = bihp[n] + bhhp[n]; }
    if (tid >= 64 && tid < 144){ int q = tid-64; int cc = q>>3, c = q&7;
      wOutL[cc][c] = Wout[(size_t)cc*1024 + dirC*512 + ncC*8 + c]; } }
  // Te slice -> 32 VGPRs (row r = wave+8k, 8 bf16 at h0)
  bf16x8 teR[8];
  { const u16* Te = (const u16*)(ws+OFF_TE);
    #pragma unroll
    for (int k = 0; k < 8; ++k){
      int r = wave + 8*k; int ci = r >> 5, u = r & 31;
      int s = (ci ? s0B : s0A) + u;
      teR[k] = *(const bf16x8*)(Te + ((size_t)(ab*S_ + s))*H_ + h0); } }
  // EMB slice -> 64 VGPRs (tid<384: 8 cols cg*8.. x 16 rows rq*16..)
  bf16x8 embR[16];
  if (tid < 384){
    const u16* E = (const u16*)(ws+OFF_EMB);
    #pragma unroll
    for (int j = 0; j < 16; ++j){
      int r = rq*16 + j;
      int s = (r < 32) ? (s0A + r) : (s0B + (r - 32));
      embR[j] = *(const bf16x8*)(E + ((size_t)(ab*S_ + s))*I_ + cg*8); } }
  __syncthreads();

  for (int t = 0; t < S_; ++t){
    // ===== phase A: dec/Td, h@Whh^T, x_t@WihR^T (B-operands from LDS); zero ctx/sumE =====
    {
      const u16* hB = (const u16*)(ws+OFF_H);
      if (wave < 2){                 // Whh tile: m-half = wave
        int m0 = dirA*32 + wave*16;
        const u16* ap = hB + (size_t)(m0+lr)*H_ + lkb;
        f32x4 acc = {0.f,0.f,0.f,0.f};
        for (int k = 0; k < H_; k += 32){
          bf16x8 a = *(const bf16x8*)(ap + k);
          bf16x8 b = *(const bf16x8*)(&wWhh[lr][k + lkb]);
          acc = __builtin_amdgcn_mfma_f32_16x16x32_bf16(a, b, acc, 0, 0, 0);
        }
        float* o = (float*)(ws+OFF_HWH);
        #pragma unroll
        for (int q = 0; q < 4; q++)
          o[(size_t)(m0 + row4 + q)*G4H + n0A*16 + lr] = acc[q];
      } else if (wave < 4){          // WIR tile: batch-half = wave-2
        int bbase = (wave-2)*16;
        int trow = dirA ? (S_-1-t) : t;
        const u16* E = (const u16*)(ws+OFF_EMB);
        const u16* ap = E + ((size_t)(bbase+lr)*S_ + trow)*I_ + lkb;
        f32x4 acc = {0.f,0.f,0.f,0.f};
        for (int k = 0; k < I_; k += 32){
          bf16x8 a = *(const bf16x8*)(ap + k);
          bf16x8 b = *(const bf16x8*)(&wWIR[lr][k + lkb]);
          acc = __builtin_amdgcn_mfma_f32_16x16x32_bf16(a, b, acc, 0, 0, 0);
        }
        float* o = (float*)(ws+OFF_XW);
        #pragma unroll
        for (int q = 0; q < 4; q++)
          o[(size_t)(dirA*32 + bbase + row4 + q)*G4H + n0A*16 + lr] = acc[q];
      } else if (blk < 32){          // dec tile: m-quarter = wave-4
        int m0 = (wave-4)*16;
        const u16* ap = hB + (size_t)(m0+lr)*H_ + lkb;
        f32x4 acc = {0.f,0.f,0.f,0.f};
        for (int k = 0; k < H_; k += 32){
          bf16x8 a = *(const bf16x8*)(ap + k);
          bf16x8 b = *(const bf16x8*)(&wDec[lr][k + lkb]);
          acc = __builtin_amdgcn_mfma_f32_16x16x32_bf16(a, b, acc, 0, 0, 0);
        }
        float* Td = (float*)(ws+OFF_TD);
        #pragma unroll
        for (int q = 0; q < 4; q++){
          int rr = m0 + row4 + q, cc = blk*16 + lr;
          Td[rr*H_ + cc] = tanhf(acc[q] + bdec[cc]);
        }
      } else {                       // zero ctx & sumE
        int zid = (((blk-32)<<2) + (wave-4))*64 + lane;   // covers 49152+64
        float* ctx = (float*)(ws+OFF_CTX);
        if (zid < R_*I_) ctx[zid] = 0.f;
        if (zid < R_) ((float*)(ws+OFF_SUME))[zid] = 0.f;
      }
    }
    gridbar(bar, ++gen);
    // ===== phase B: scores (tanh-identity, Te in regs), exp, ctx gather (EMB in regs) =====
    {
      const float* Td = (const float*)(ws+OFF_TD);
      const float* mbp = (const float*)(ws+OFF_M);
      float tdf[8], tdb[8], va[8];
      #pragma unroll
      for (int j = 0; j < 8; j++){
        tdf[j] = Td[ab*H_ + h0 + j];
        tdb[j] = Td[(32+ab)*H_ + h0 + j];
        va[j]  = v[h0 + j];
      }
      float mF = mbp[ab], mB = mbp[32+ab];
      #pragma unroll
      for (int k = 0; k < 8; ++k){
        int r = wave + 8*k;
        int ci = r >> 5, u = r & 31;
        bf16x8 tv = teR[k];
        float af = 0.f, ab2 = 0.f;
        #pragma unroll
        for (int j = 0; j < 8; ++j){
          float te = bf2f((u16)tv[j]);
          float df = fmaf(te, tdf[j], 1.0f);
          float db = fmaf(te, tdb[j], 1.0f);
          af  = fmaf((te+tdf[j])*frcp(df), va[j], af);
          ab2 = fmaf((te+tdb[j])*frcp(db), va[j], ab2);
        }
        #pragma unroll
        for (int off = 1; off < 64; off <<= 1){
          af  += __shfl_xor(af, off);
          ab2 += __shfl_xor(ab2, off);
        }
        float ef = __expf(fminf(fmaxf(af  - mF, -80.f), 80.f));
        float eb = __expf(fminf(fmaxf(ab2 - mB, -80.f), 80.f));
        if (lane == 0){ sh.b.ldsE[0][ci][u] = ef; sh.b.ldsE[1][ci][u] = eb; }
      }
      __syncthreads();
      if (tid < 2){
        float s = 0.f;
        for (int ci = 0; ci < 2; ci++)
          for (int u = 0; u < 32; u++) s += sh.b.ldsE[tid][ci][u];
        atomicAdd((float*)(ws+OFF_SUME) + tid*32 + ab, s);
      }
      if (tid < 384){
        const int ci = rq >> 1;
        float cf[8] = {0,0,0,0,0,0,0,0}, cb[8] = {0,0,0,0,0,0,0,0};
        #pragma unroll
        for (int j = 0; j < 16; ++j){
          int u = ((rq & 1) << 4) + j;
          float wf = sh.b.ldsE[0][ci][u];
          float wb = sh.b.ldsE[1][1-ci][31-u];   // emb[s] pairs with e_b[S-1-s]
          bf16x8 e = embR[j];
          #pragma unroll
          for (int x = 0; x < 8; ++x){
            float ev = bf2f((u16)e[x]);
            cf[x] = fmaf(wf, ev, cf[x]);
            cb[x] = fmaf(wb, ev, cb[x]);
          }
        }
        #pragma unroll
        for (int x = 0; x < 8; ++x){
          sh.b.cpart[rq][cg][x]   = cf[x];
          sh.b.cpart[rq][cg][8+x] = cb[x];
        }
      }
      __syncthreads();
      {
        float* ctxg = (float*)(ws+OFF_CTX);
        for (int o = tid; o < 1536; o += NTHR){
          int d = (o >= 768) ? 1 : 0;
          int col = o - d*768;
          int cgx = col >> 3, c = col & 7;
          float s = sh.b.cpart[0][cgx][d*8+c] + sh.b.cpart[1][cgx][d*8+c]
                  + sh.b.cpart[2][cgx][d*8+c] + sh.b.cpart[3][cgx][d*8+c];
          atomicAdd(&ctxg[(size_t)(d*32+ab)*I_ + col], s);
        }
      }
    }
    gridbar(bar, ++gen);
    // ===== phase C: ctx@WihL^T (LDS weights), LSTM cell, out projection =====
    {
      const float* se = (const float*)(ws+OFF_SUME) + dirC*32 + qbC*16;
      if (tid < 16){
        float s_ = se[tid];
        sh.c.sum[tid] = s_;
        sh.c.inv[tid] = 1.0f / fmaxf(s_, 1e-30f);
      }
      __syncthreads();
      const float* ctx = (const float*)(ws+OFF_CTX) + (size_t)(dirC*32 + qbC*16)*I_;
      for (int idx = tid; idx < 16*I_; idx += NTHR){
        int j = idx / I_, k = idx - j*I_;
        sh.c.Abuf[j][k] = f2bf(ctx[(size_t)j*I_ + k] * sh.c.inv[j]);
      }
      __syncthreads();
      f32x4 acc = {0.f,0.f,0.f,0.f};
      if (wave < 2){                 // GEMM: M=16 batches, N=32 packed gate-rows, K=768
        for (int k = 0; k < I_; k += 32){
          bf16x8 av = *(const bf16x8*)(&sh.c.Abuf[lr][k + lkb]);
          bf16x8 bv = *(const bf16x8*)(&wWIL[wave*16 + lr][k + lkb]);
          acc = __builtin_amdgcn_mfma_f32_16x16x32_bf16(av, bv, acc, 0, 0, 0);
        }
      } else {                       // Gpre = xW + hW + biases for 32 pr x 16 batches
        const float* xW = (const float*)(ws+OFF_XW);
        const float* hW = (const float*)(ws+OFF_HWH);
        for (int ii = tid - 128; ii < 512; ii += 384){
          int pr = ii >> 4, j = ii & 15;
          int g = pr >> 3, c = pr & 7;
          int n = g*512 + ncC*8 + c;
          size_t rr = (size_t)(dirC*32 + qbC*16 + j);
          sh.c.Gpre[pr][j] = xW[rr*G4H + n] + hW[rr*G4H + n] + bsumL[pr];
        }
      }
      __syncthreads();
      if (wave < 2){
        int pr = wave*16 + lr;
        #pragma unroll
        for (int q = 0; q < 4; q++){
          int j = row4 + q;
          sh.c.Gs[pr][j] = acc[q] + sh.c.Gpre[pr][j];
        }
      }
      __syncthreads();
      float* cS = (float*)(ws+OFF_C);
      u16* hBw = (u16*)(ws+OFF_H);
      if (tid < 128){
        int j = tid >> 3, c = tid & 7;
        int hg = ncC*8 + c;
        size_t rr = (size_t)(dirC*32 + qbC*16 + j);
        float ig = sigm(sh.c.Gs[c][j]);
        float fg = sigm(sh.c.Gs[8+c][j]);
        float gg = tanhf(sh.c.Gs[16+c][j]);
        float og = sigm(sh.c.Gs[24+c][j]);
        float cn = fmaf(fg, cS[rr*H_ + hg], ig*gg);
        float hn = og * tanhf(cn);
        cS[rr*H_ + hg] = cn;
        hBw[rr*H_ + hg] = f2bf(hn);
        sh.c.Hb[j][c] = hn;
      }
      __syncthreads();
      if (tid < 160){
        int j = tid/10, cc = tid - j*10;
        float s = 0.f;
        #pragma unroll
        for (int c = 0; c < 8; c++) s = fmaf(sh.c.Hb[j][c], wOutL[cc][c], s);
        if (dirC == 0 && ncC == 0) s += bout[cc];
        int bb = qbC*16 + j;
        int st = dirC ? (S_-1-t) : t;
        atomicAdd(&out[((size_t)bb*S_ + st)*C_ + cc], s);
      }
      if (ncC == 0 && tid < 16){
        float* mbp = (float*)(ws+OFF_M);
        mbp[dirC*32 + qbC*16 + tid] += logf(fmaxf(sh.c.sum[tid], 1e-30f));
      }
    }
    gridbar(bar, ++gen);
  }
}

// ---------------- host launcher ----------------
extern "C" void kernel_launch(void* const* d_in, const int* in_sizes, int n_in,
                              void* d_out, int out_size, void* d_ws, size_t ws_size,
                              hipStream_t stream){
  const float* emb   = (const float*)d_in[0];
  const float* Wenc  = (const float*)d_in[1];
  const float* benc  = (const float*)d_in[2];
  const float* Wdec  = (const float*)d_in[3];
  const float* bdec  = (const float*)d_in[4];
  const float* v     = (const float*)d_in[5];
  const float* Wih_f = (const float*)d_in[6];
  const float* Whh_f = (const float*)d_in[7];
  const float* bih_f = (const float*)d_in[8];
  const float* bhh_f = (const float*)d_in[9];
  const float* Wih_b = (const float*)d_in[10];
  const float* Whh_b = (const float*)d_in[11];
  const float* bih_b = (const float*)d_in[12];
  const float* bhh_b = (const float*)d_in[13];
  const float* Wout  = (const float*)d_in[14];
  const float* bout  = (const float*)d_in[15];
  float* out = (float*)d_out;
  char* ws = (char*)d_ws;
  if (ws_size < WS_NEED) return;   // fail loudly via validation

  k_setup<<<dim3(512), dim3(256), 0, stream>>>(ws, Wenc, Wdec, Whh_f, Whh_b, Wih_f, Wih_b, out);
  k_embconv<<<dim3(2048), dim3(256), 0, stream>>>(ws, emb);
  k_enc<<<dim3(8192), dim3(256), 0, stream>>>(ws, benc);
  k_persist<<<dim3(NBLK), dim3(NTHR), 0, stream>>>(ws, bdec, v,
      bih_f, bhh_f, bih_b, bhh_b, Wout, bout, out);
}

// Round 7
// 26210.406 us; speedup vs baseline: 2.3480x; 1.0485x over previous
//
#include <hip/hip_runtime.h>
#include <stdint.h>

#define DEVINL __device__ __forceinline__

constexpr int B_  = 32;
constexpr int S_  = 512;
constexpr int I_  = 768;
constexpr int H_  = 512;
constexpr int C_  = 10;
constexpr int R_  = 64;     // 2 dirs * B_
constexpr int G4H = 2048;   // 4*H_
constexpr int I2_ = 1536;   // 2*I_
constexpr int NBLK = 256;   // persistent grid (1 block/CU co-resident)
constexpr int NTHR = 512;

using bf16x8 = __attribute__((ext_vector_type(8))) short;
using f32x4  = __attribute__((ext_vector_type(4))) float;
typedef unsigned short u16;
typedef unsigned int   u32;

// ---------------- workspace layout (bytes) ----------------
constexpr size_t OFF_TE   = 0;                                   // u16 [B_*S_][H_]  tanh(enc_proj)
constexpr size_t OFF_EMB  = OFF_TE   + (size_t)B_*S_*H_*2;       // u16 [B_*S_][I_]  embeds bf16
constexpr size_t OFF_WDEC = OFF_EMB  + (size_t)B_*S_*I_*2;       // u16 [H_][H_]
constexpr size_t OFF_WHH  = OFF_WDEC + (size_t)H_*H_*2;          // u16 [2][G4H][H_]
constexpr size_t OFF_WIL  = OFF_WHH  + (size_t)2*G4H*H_*2;       // u16 [2][G4H][I_] Wih cols 0..767
constexpr size_t OFF_WIR  = OFF_WIL  + (size_t)2*G4H*I_*2;       // u16 [2][G4H][I_] Wih cols 768..1535
constexpr size_t OFF_WENC = OFF_WIR  + (size_t)2*G4H*I_*2;       // u16 [H_][I_]
constexpr size_t OFF_H    = OFF_WENC + (size_t)H_*I_*2;          // u16 [R_][H_]   h state (bf16)
constexpr size_t OFF_C    = OFF_H    + (size_t)R_*H_*2;          // f32 [R_][H_]   c state
constexpr size_t OFF_TD   = OFF_C    + (size_t)R_*H_*4;          // f32 [R_][H_]   tanh(dec)
constexpr size_t OFF_HWH  = OFF_TD   + (size_t)R_*H_*4;          // f32 [R_][G4H]  h @ Whh^T
constexpr size_t OFF_XW   = OFF_HWH  + (size_t)R_*G4H*4;         // f32 [R_][G4H]  x_t @ WihR^T
constexpr size_t OFF_CTX  = OFF_XW   + (size_t)R_*G4H*4;         // f32 [R_][I_]   unnormalized ctx
constexpr size_t OFF_SUME = OFF_CTX  + (size_t)R_*I_*4;          // f32 [R_]
constexpr size_t OFF_M    = OFF_SUME + 256;                      // f32 [R_] running logsumexp shift
constexpr size_t OFF_BAR  = OFF_M    + 256;
constexpr int    BAR_W    = 64 + 32*32;                          // 1088 u32 words
constexpr size_t WS_NEED  = OFF_BAR + BAR_W*4;

// ---------------- helpers ----------------
DEVINL float asf(u32 u){ union{u32 i; float f;} x; x.i=u; return x.f; }
DEVINL u32   asu(float f){ union{u32 i; float f;} x; x.f=f; return x.i; }
DEVINL float bf2f(u16 h){ return asf((u32)h << 16); }
DEVINL u16   f2bf(float f){ u32 u = asu(f); return (u16)((u + 0x7fffu + ((u>>16)&1u)) >> 16); }
DEVINL float frcp(float x){
#if __has_builtin(__builtin_amdgcn_rcpf)
  return __builtin_amdgcn_rcpf(x);
#else
  return 1.0f/x;
#endif
}
DEVINL float sigm(float x){ return frcp(1.0f + __expf(-x)); }

// per-access coherent (sc0 sc1) ops: read/write the IC coherence point
// directly -> no agent-scope fences (no L2 writeback/invalidate) needed.
DEVINL float ldc_f(const float* p){ return __hip_atomic_load(p, __ATOMIC_RELAXED, __HIP_MEMORY_SCOPE_AGENT); }
DEVINL void  stc_f(float* p, float v){ __hip_atomic_store(p, v, __ATOMIC_RELAXED, __HIP_MEMORY_SCOPE_AGENT); }
DEVINL u32   ldc_u(const u32* p){ return __hip_atomic_load(p, __ATOMIC_RELAXED, __HIP_MEMORY_SCOPE_AGENT); }
DEVINL void  stc_u(u32* p, u32 v){ __hip_atomic_store(p, v, __ATOMIC_RELAXED, __HIP_MEMORY_SCOPE_AGENT); }
DEVINL void  addc_f(float* p, float v){ __hip_atomic_fetch_add(p, v, __ATOMIC_RELAXED, __HIP_MEMORY_SCOPE_AGENT); }

// grid barrier, 2-level tree, FENCE-FREE: all cross-block data moves via
// sc0sc1 accesses (complete at IC before the pre-arrival __syncthreads
// drains vmcnt), so no L2 writeback/invalidate is required for visibility.
DEVINL void gridbar(u32* bar, u32 n){
  __syncthreads();   // compiler drains vmcnt before s_barrier -> sc-stores at IC
  if (threadIdx.x == 0){
    u32 g = blockIdx.x >> 3;
    u32 old = __hip_atomic_fetch_add(&bar[64 + g*32], 1u, __ATOMIC_RELAXED, __HIP_MEMORY_SCOPE_AGENT);
    if (old == n*8u - 1u){
      u32 r = __hip_atomic_fetch_add(&bar[0], 1u, __ATOMIC_RELAXED, __HIP_MEMORY_SCOPE_AGENT);
      if (r == n*32u - 1u){
        __hip_atomic_store(&bar[32], n, __ATOMIC_RELAXED, __HIP_MEMORY_SCOPE_AGENT);
      }
    }
    while (__hip_atomic_load(&bar[32], __ATOMIC_RELAXED, __HIP_MEMORY_SCOPE_AGENT) < n)
      __builtin_amdgcn_s_sleep(2);
  }
  __syncthreads();
}

// M=16 GEMM over K=512 with A = 16 rows of h (coherent loads, batched 32
// dwords ahead of use) and B = pinned LDS panel [16][520].
DEVINL f32x4 gemm_h16(const u32* h32, size_t base, const u16 (*W)[520], int lr, int lkb){
  f32x4 acc = {0.f,0.f,0.f,0.f};
  #pragma unroll
  for (int half = 0; half < 2; ++half){
    u32 hreg[32];
    #pragma unroll
    for (int i2 = 0; i2 < 32; ++i2)
      hreg[i2] = ldc_u(h32 + base + half*128 + (i2>>2)*16 + (i2&3));
    #pragma unroll
    for (int ki = 0; ki < 8; ++ki){
      union { bf16x8 v; u32 w[4]; } ua;
      ua.w[0]=hreg[ki*4+0]; ua.w[1]=hreg[ki*4+1];
      ua.w[2]=hreg[ki*4+2]; ua.w[3]=hreg[ki*4+3];
      bf16x8 b = *(const bf16x8*)(&W[lr][(half*8+ki)*32 + lkb]);
      acc = __builtin_amdgcn_mfma_f32_16x16x32_bf16(ua.v, b, acc, 0, 0, 0);
    }
  }
  return acc;
}

// ---------------- shared-memory union (phase-transient) ----------------
struct SMemB { float ldsE[2][2][32]; float cpart[4][96][16]; };           // 25088 B
struct SMemC { u16 Abuf[16][776]; float Gpre[32][16]; float Gs[32][16];
               float Hb[16][8]; float inv[16]; float sum[16]; };          // 29568 B
union alignas(16) SMem { SMemB b; SMemC c; };

// ---------------- one-time setup: zero state, convert weights ----------------
__global__ void k_setup(char* ws, const float* Wenc, const float* Wdec,
                        const float* Whh_f, const float* Whh_b,
                        const float* Wih_f, const float* Wih_b,
                        float* out){
  int tid = blockIdx.x*blockDim.x + threadIdx.x;
  int nth = gridDim.x*blockDim.x;
  for (int i = tid; i < B_*S_*C_; i += nth) out[i] = 0.f;
  u16* hB = (u16*)(ws+OFF_H);
  for (int i = tid; i < R_*H_; i += nth) hB[i] = 0;
  float* cS = (float*)(ws+OFF_C);
  for (int i = tid; i < R_*H_; i += nth) cS[i] = 0.f;
  float* mb = (float*)(ws+OFF_M);
  for (int i = tid; i < R_; i += nth) mb[i] = 0.f;
  u32* bar = (u32*)(ws+OFF_BAR);
  for (int i = tid; i < BAR_W; i += nth) bar[i] = 0u;
  u16* wd = (u16*)(ws+OFF_WDEC);
  for (int i = tid; i < H_*H_; i += nth) wd[i] = f2bf(Wdec[i]);
  u16* we = (u16*)(ws+OFF_WENC);
  for (int i = tid; i < H_*I_; i += nth) we[i] = f2bf(Wenc[i]);
  u16* wh = (u16*)(ws+OFF_WHH);
  for (int i = tid; i < G4H*H_; i += nth){
    wh[i] = f2bf(Whh_f[i]);
    wh[G4H*H_ + i] = f2bf(Whh_b[i]);
  }
  u16* wl = (u16*)(ws+OFF_WIL);
  u16* wr = (u16*)(ws+OFF_WIR);
  for (int i = tid; i < G4H*I_; i += nth){
    int n = i / I_, k = i - n*I_;
    wl[i]            = f2bf(Wih_f[n*I2_ + k]);
    wr[i]            = f2bf(Wih_f[n*I2_ + I_ + k]);
    wl[G4H*I_ + i]   = f2bf(Wih_b[n*I2_ + k]);
    wr[G4H*I_ + i]   = f2bf(Wih_b[n*I2_ + I_ + k]);
  }
}

// ---------------- one-time: embeds -> bf16 ----------------
__global__ void k_embconv(char* ws, const float* emb){
  u16* e = (u16*)(ws+OFF_EMB);
  int tid = blockIdx.x*blockDim.x + threadIdx.x;
  int nth = gridDim.x*blockDim.x;
  int n4 = (B_*S_*I_)/4;
  const float4* src = (const float4*)emb;
  ushort4* dst = (ushort4*)e;
  for (int i = tid; i < n4; i += nth){
    float4 x = src[i];
    ushort4 o;
    o.x = f2bf(x.x); o.y = f2bf(x.y); o.z = f2bf(x.z); o.w = f2bf(x.w);
    dst[i] = o;
  }
}

// ---------------- one-time: Te = tanh(embB @ WencB^T + benc) ----------------
__global__ __launch_bounds__(256) void k_enc(char* ws, const float* benc){
  const u16* A = (const u16*)(ws+OFF_EMB);
  const u16* W = (const u16*)(ws+OFF_WENC);
  u16* Te = (u16*)(ws+OFF_TE);
  int wg = blockIdx.x;
  int mt = wg >> 3, ng = wg & 7;
  int wave = threadIdx.x >> 6, lane = threadIdx.x & 63;
  int m0 = mt*16, n0 = ng*64 + wave*16;
  int lr = lane & 15, lkb = (lane>>4)*8;
  const u16* ap = A + (size_t)(m0+lr)*I_ + lkb;
  const u16* bp = W + (size_t)(n0+lr)*I_ + lkb;
  f32x4 acc = {0.f,0.f,0.f,0.f};
  for (int k = 0; k < I_; k += 32){
    bf16x8 a = *(const bf16x8*)(ap + k);
    bf16x8 b = *(const bf16x8*)(bp + k);
    acc = __builtin_amdgcn_mfma_f32_16x16x32_bf16(a, b, acc, 0, 0, 0);
  }
  int row4 = (lane>>4)*4;
  #pragma unroll
  for (int q = 0; q < 4; q++){
    int rr = m0 + row4 + q, cc = n0 + lr;
    Te[(size_t)rr*H_ + cc] = f2bf(tanhf(acc[q] + benc[cc]));
  }
}

// ---------------- persistent stepper: weight-stationary, fence-free sync ----------------
__global__ __launch_bounds__(NTHR) void k_persist(char* ws,
        const float* bdec, const float* v,
        const float* bih_f, const float* bhh_f,
        const float* bih_b, const float* bhh_b,
        const float* Wout, const float* bout, float* out){
  __shared__ SMem sh;
  __shared__ alignas(16) u16 wWhh[16][520];   // (dirA,n0A): Whh rows n0A*16..+15
  __shared__ alignas(16) u16 wWIR[16][776];   // (dirA,n0A): WihR rows n0A*16..+15
  __shared__ alignas(16) u16 wDec[16][520];   // blk<32: Wdec rows blk*16..+15
  __shared__ alignas(16) u16 wWIL[32][776];   // (dirC,ncC): packed [g*8+j] = WihL row g*512+ncC*8+j
  __shared__ float wOutL[10][8];
  __shared__ float bsumL[32];
  u32* bar = (u32*)(ws+OFF_BAR);
  u32 gen = 0;
  const int tid = threadIdx.x, lane = tid & 63, wave = tid >> 6;
  const int lr = lane & 15, lkb = (lane>>4)*8, row4 = (lane>>4)*4;
  const int blk = blockIdx.x;
  const int dirA = blk & 1, n0A = blk >> 1;
  const int ab   = blk & 31, pair = blk >> 5;
  const int s0A  = pair*32, s0B = S_ - pair*32 - 32;
  const int h0   = lane*8;
  const int cg   = (tid < 384) ? (tid % 96) : 0;
  const int rq   = (tid < 384) ? (tid / 96) : 0;
  const int dirC = blk >> 7, ncC = (blk >> 1) & 63, qbC = blk & 1;

  // ---- prologue: pin weights into LDS ----
  { const u16* src = (const u16*)(ws+OFF_WHH) + (size_t)dirA*G4H*H_ + (size_t)n0A*16*H_;
    for (int idx = tid; idx < 16*64; idx += NTHR){ int r = idx>>6, c8 = idx&63;
      *(uint4*)&wWhh[r][c8*8] = *(const uint4*)(src + (size_t)r*H_ + c8*8); } }
  { const u16* src = (const u16*)(ws+OFF_WIR) + (size_t)dirA*G4H*I_ + (size_t)n0A*16*I_;
    for (int idx = tid; idx < 16*96; idx += NTHR){ int r = idx/96, c8 = idx - r*96;
      *(uint4*)&wWIR[r][c8*8] = *(const uint4*)(src + (size_t)r*I_ + c8*8); } }
  if (blk < 32){
    const u16* src = (const u16*)(ws+OFF_WDEC) + (size_t)blk*16*H_;
    for (int idx = tid; idx < 16*64; idx += NTHR){ int r = idx>>6, c8 = idx&63;
      *(uint4*)&wDec[r][c8*8] = *(const uint4*)(src + (size_t)r*H_ + c8*8); } }
  { const u16* src = (const u16*)(ws+OFF_WIL) + (size_t)dirC*G4H*I_;
    for (int idx = tid; idx < 32*96; idx += NTHR){ int pr = idx/96, c8 = idx - pr*96;
      int g = pr>>3, j = pr&7;
      *(uint4*)&wWIL[pr][c8*8] = *(const uint4*)(src + (size_t)(g*512 + ncC*8 + j)*I_ + c8*8); } }
  { const float* bihp = dirC ? bih_b : bih_f;
    const float* bhhp = dirC ? bhh_b : bhh_f;
    if (tid < 32){ int g = tid>>3, c = tid&7; int n = g*512 + ncC*8 + c;
      bsumL[tid] = bihp[n] + bhhp[n]; }
    if (tid >= 64 && tid < 144){ int q = tid-64; int cc = q>>3, c = q&7;
      wOutL[cc][c] = Wout[(size_t)cc*1024 + dirC*512 + ncC*8 + c]; } }
  // Te slice -> 32 VGPRs
  bf16x8 teR[8];
  { const u16* Te = (const u16*)(ws+OFF_TE);
    #pragma unroll
    for (int k = 0; k < 8; ++k){
      int r = wave + 8*k; int ci = r >> 5, u = r & 31;
      int s = (ci ? s0B : s0A) + u;
      teR[k] = *(const bf16x8*)(Te + ((size_t)(ab*S_ + s))*H_ + h0); } }
  // EMB slice -> 64 VGPRs (tid<384)
  bf16x8 embR[16];
  if (tid < 384){
    const u16* E = (const u16*)(ws+OFF_EMB);
    #pragma unroll
    for (int j = 0; j < 16; ++j){
      int r = rq*16 + j;
      int s = (r < 32) ? (s0A + r) : (s0B + (r - 32));
      embR[j] = *(const bf16x8*)(E + ((size_t)(ab*S_ + s))*I_ + cg*8); } }
  __syncthreads();

  for (int t = 0; t < S_; ++t){
    // ===== phase A: dec/Td, h@Whh^T (coherent h loads); zero ctx/sumE =====
    {
      const u32* h32 = (const u32*)(ws+OFF_H);
      if (wave < 2){                 // Whh tile
        int m0 = dirA*32 + wave*16;
        size_t base = (((size_t)(m0+lr))*H_ + lkb) >> 1;
        f32x4 acc = gemm_h16(h32, base, wWhh, lr, lkb);
        float* o = (float*)(ws+OFF_HWH);
        #pragma unroll
        for (int q = 0; q < 4; q++)
          stc_f(&o[(size_t)(m0 + row4 + q)*G4H + n0A*16 + lr], acc[q]);
      } else if (wave < 4){          // WIR tile (EMB is immutable -> plain loads)
        int bbase = (wave-2)*16;
        int trow = dirA ? (S_-1-t) : t;
        const u16* E = (const u16*)(ws+OFF_EMB);
        const u16* ap = E + ((size_t)(bbase+lr)*S_ + trow)*I_ + lkb;
        f32x4 acc = {0.f,0.f,0.f,0.f};
        for (int k = 0; k < I_; k += 32){
          bf16x8 a = *(const bf16x8*)(ap + k);
          bf16x8 b = *(const bf16x8*)(&wWIR[lr][k + lkb]);
          acc = __builtin_amdgcn_mfma_f32_16x16x32_bf16(a, b, acc, 0, 0, 0);
        }
        float* o = (float*)(ws+OFF_XW);
        #pragma unroll
        for (int q = 0; q < 4; q++)
          stc_f(&o[(size_t)(dirA*32 + bbase + row4 + q)*G4H + n0A*16 + lr], acc[q]);
      } else if (blk < 32){          // dec tile
        int m0 = (wave-4)*16;
        size_t base = (((size_t)(m0+lr))*H_ + lkb) >> 1;
        f32x4 acc = gemm_h16(h32, base, wDec, lr, lkb);
        float* Td = (float*)(ws+OFF_TD);
        #pragma unroll
        for (int q = 0; q < 4; q++){
          int rr = m0 + row4 + q, cc = blk*16 + lr;
          stc_f(&Td[rr*H_ + cc], tanhf(acc[q] + bdec[cc]));
        }
      } else {                       // zero ctx & sumE
        int zid = (((blk-32)<<2) + (wave-4))*64 + lane;
        float* ctx = (float*)(ws+OFF_CTX);
        if (zid < R_*I_) stc_f(&ctx[zid], 0.f);
        if (zid < R_) stc_f((float*)(ws+OFF_SUME) + zid, 0.f);
      }
    }
    gridbar(bar, ++gen);
    // ===== phase B: scores (tanh-identity, Te in regs), exp, ctx gather =====
    {
      const float* Td = (const float*)(ws+OFF_TD);
      const float* mbp = (const float*)(ws+OFF_M);
      float tdf[8], tdb[8], va[8];
      #pragma unroll
      for (int j = 0; j < 8; j++){
        tdf[j] = ldc_f(&Td[ab*H_ + h0 + j]);
        tdb[j] = ldc_f(&Td[(32+ab)*H_ + h0 + j]);
        va[j]  = v[h0 + j];
      }
      float mF = ldc_f(&mbp[ab]), mB = ldc_f(&mbp[32+ab]);
      #pragma unroll
      for (int k = 0; k < 8; ++k){
        int r = wave + 8*k;
        int ci = r >> 5, u = r & 31;
        bf16x8 tv = teR[k];
        float af = 0.f, ab2 = 0.f;
        #pragma unroll
        for (int j = 0; j < 8; ++j){
          float te = bf2f((u16)tv[j]);
          float df = fmaf(te, tdf[j], 1.0f);
          float db = fmaf(te, tdb[j], 1.0f);
          af  = fmaf((te+tdf[j])*frcp(df), va[j], af);
          ab2 = fmaf((te+tdb[j])*frcp(db), va[j], ab2);
        }
        #pragma unroll
        for (int off = 1; off < 64; off <<= 1){
          af  += __shfl_xor(af, off);
          ab2 += __shfl_xor(ab2, off);
        }
        float ef = __expf(fminf(fmaxf(af  - mF, -80.f), 80.f));
        float eb = __expf(fminf(fmaxf(ab2 - mB, -80.f), 80.f));
        if (lane == 0){ sh.b.ldsE[0][ci][u] = ef; sh.b.ldsE[1][ci][u] = eb; }
      }
      __syncthreads();
      if (tid < 2){
        float s = 0.f;
        for (int ci = 0; ci < 2; ci++)
          for (int u = 0; u < 32; u++) s += sh.b.ldsE[tid][ci][u];
        addc_f((float*)(ws+OFF_SUME) + tid*32 + ab, s);
      }
      if (tid < 384){
        const int ci = rq >> 1;
        float cf[8] = {0,0,0,0,0,0,0,0}, cb[8] = {0,0,0,0,0,0,0,0};
        #pragma unroll
        for (int j = 0; j < 16; ++j){
          int u = ((rq & 1) << 4) + j;
          float wf = sh.b.ldsE[0][ci][u];
          float wb = sh.b.ldsE[1][1-ci][31-u];
          bf16x8 e = embR[j];
          #pragma unroll
          for (int x = 0; x < 8; ++x){
            float ev = bf2f((u16)e[x]);
            cf[x] = fmaf(wf, ev, cf[x]);
            cb[x] = fmaf(wb, ev, cb[x]);
          }
        }
        #pragma unroll
        for (int x = 0; x < 8; ++x){
          sh.b.cpart[rq][cg][x]   = cf[x];
          sh.b.cpart[rq][cg][8+x] = cb[x];
        }
      }
      __syncthreads();
      {
        float* ctxg = (float*)(ws+OFF_CTX);
        for (int o = tid; o < 1536; o += NTHR){
          int d = (o >= 768) ? 1 : 0;
          int col = o - d*768;
          int cgx = col >> 3, c = col & 7;
          float s = sh.b.cpart[0][cgx][d*8+c] + sh.b.cpart[1][cgx][d*8+c]
                  + sh.b.cpart[2][cgx][d*8+c] + sh.b.cpart[3][cgx][d*8+c];
          addc_f(&ctxg[(size_t)(d*32+ab)*I_ + col], s);
        }
      }
    }
    gridbar(bar, ++gen);
    // ===== phase C: ctx@WihL^T (LDS weights), LSTM cell, out projection =====
    {
      const float* se = (const float*)(ws+OFF_SUME) + dirC*32 + qbC*16;
      if (tid < 16){
        float s_ = ldc_f(&se[tid]);
        sh.c.sum[tid] = s_;
        sh.c.inv[tid] = 1.0f / fmaxf(s_, 1e-30f);
      }
      __syncthreads();
      {  // batched coherent ctx read: thread t owns row t/32, cols (t%32)*24..+23
        const float* ctx = (const float*)(ws+OFF_CTX) + (size_t)(dirC*32 + qbC*16)*I_;
        float creg[24];
        int j = tid >> 5, k0 = (tid & 31) * 24;
        #pragma unroll
        for (int i2 = 0; i2 < 24; ++i2)
          creg[i2] = ldc_f(ctx + (size_t)j*I_ + k0 + i2);
        float inv = sh.c.inv[j];
        #pragma unroll
        for (int i2 = 0; i2 < 24; ++i2)
          sh.c.Abuf[j][k0 + i2] = f2bf(creg[i2] * inv);
      }
      __syncthreads();
      f32x4 acc = {0.f,0.f,0.f,0.f};
      if (wave < 2){                 // GEMM: M=16 batches, N=32 packed gate-rows, K=768
        for (int k = 0; k < I_; k += 32){
          bf16x8 av = *(const bf16x8*)(&sh.c.Abuf[lr][k + lkb]);
          bf16x8 bv = *(const bf16x8*)(&wWIL[wave*16 + lr][k + lkb]);
          acc = __builtin_amdgcn_mfma_f32_16x16x32_bf16(av, bv, acc, 0, 0, 0);
        }
      } else {                       // Gpre = xW + hW + biases
        const float* xW = (const float*)(ws+OFF_XW);
        const float* hW = (const float*)(ws+OFF_HWH);
        for (int ii = tid - 128; ii < 512; ii += 384){
          int pr = ii >> 4, j = ii & 15;
          int g = pr >> 3, c = pr & 7;
          int n = g*512 + ncC*8 + c;
          size_t rr = (size_t)(dirC*32 + qbC*16 + j);
          sh.c.Gpre[pr][j] = ldc_f(&xW[rr*G4H + n]) + ldc_f(&hW[rr*G4H + n]) + bsumL[pr];
        }
      }
      __syncthreads();
      if (wave < 2){
        int pr = wave*16 + lr;
        #pragma unroll
        for (int q = 0; q < 4; q++){
          int j = row4 + q;
          sh.c.Gs[pr][j] = acc[q] + sh.c.Gpre[pr][j];
        }
      }
      __syncthreads();
      float* cS = (float*)(ws+OFF_C);
      if (tid < 128){
        int j = tid >> 3, c = tid & 7;
        int hg = ncC*8 + c;
        size_t rr = (size_t)(dirC*32 + qbC*16 + j);
        float ig = sigm(sh.c.Gs[c][j]);
        float fg = sigm(sh.c.Gs[8+c][j]);
        float gg = tanhf(sh.c.Gs[16+c][j]);
        float og = sigm(sh.c.Gs[24+c][j]);
        float cn = fmaf(fg, cS[rr*H_ + hg], ig*gg);   // cS block-private: plain ok
        float hn = og * tanhf(cn);
        cS[rr*H_ + hg] = cn;
        sh.c.Hb[j][c] = hn;
      }
      __syncthreads();
      if (tid < 64){   // publish h as packed u32 coherent stores
        int j = tid >> 2, cp = tid & 3;
        size_t rr = (size_t)(dirC*32 + qbC*16 + j);
        u32 pk = (u32)f2bf(sh.c.Hb[j][cp*2]) | ((u32)f2bf(sh.c.Hb[j][cp*2+1]) << 16);
        stc_u((u32*)(ws+OFF_H) + ((rr*H_ + ncC*8) >> 1) + cp, pk);
      }
      if (tid < 160){
        int j = tid/10, cc = tid - j*10;
        float s = 0.f;
        #pragma unroll
        for (int c = 0; c < 8; c++) s = fmaf(sh.c.Hb[j][c], wOutL[cc][c], s);
        if (dirC == 0 && ncC == 0) s += bout[cc];
        int bb = qbC*16 + j;
        int st = dirC ? (S_-1-t) : t;
        atomicAdd(&out[((size_t)bb*S_ + st)*C_ + cc], s);
      }
      if (ncC == 0 && tid < 16){
        float* mp = (float*)(ws+OFF_M) + dirC*32 + qbC*16 + tid;
        stc_f(mp, ldc_f(mp) + logf(fmaxf(sh.c.sum[tid], 1e-30f)));
      }
    }
    gridbar(bar, ++gen);
  }
}

// ---------------- host launcher ----------------
extern "C" void kernel_launch(void* const* d_in, const int* in_sizes, int n_in,
                              void* d_out, int out_size, void* d_ws, size_t ws_size,
                              hipStream_t stream){
  const float* emb   = (const float*)d_in[0];
  const float* Wenc  = (const float*)d_in[1];
  const float* benc  = (const float*)d_in[2];
  const float* Wdec  = (const float*)d_in[3];
  const float* bdec  = (const float*)d_in[4];
  const float* v     = (const float*)d_in[5];
  const float* Wih_f = (const float*)d_in[6];
  const float* Whh_f = (const float*)d_in[7];
  const float* bih_f = (const float*)d_in[8];
  const float* bhh_f = (const float*)d_in[9];
  const float* Wih_b = (const float*)d_in[10];
  const float* Whh_b = (const float*)d_in[11];
  const float* bih_b = (const float*)d_in[12];
  const float* bhh_b = (const float*)d_in[13];
  const float* Wout  = (const float*)d_in[14];
  const float* bout  = (const float*)d_in[15];
  float* out = (float*)d_out;
  char* ws = (char*)d_ws;
  if (ws_size < WS_NEED) return;   // fail loudly via validation

  k_setup<<<dim3(512), dim3(256), 0, stream>>>(ws, Wenc, Wdec, Whh_f, Whh_b, Wih_f, Wih_b, out);
  k_embconv<<<dim3(2048), dim3(256), 0, stream>>>(ws, emb);
  k_enc<<<dim3(8192), dim3(256), 0, stream>>>(ws, benc);
  k_persist<<<dim3(NBLK), dim3(NTHR), 0, stream>>>(ws, bdec, v,
      bih_f, bhh_f, bih_b, bhh_b, Wout, bout, out);
}

// Round 8
// 25689.960 us; speedup vs baseline: 2.3955x; 1.0203x over previous
//
#include <hip/hip_runtime.h>
#include <stdint.h>

#define DEVINL __device__ __forceinline__

constexpr int B_  = 32;
constexpr int S_  = 512;
constexpr int I_  = 768;
constexpr int H_  = 512;
constexpr int C_  = 10;
constexpr int R_  = 64;     // 2 dirs * B_
constexpr int G4H = 2048;   // 4*H_
constexpr int I2_ = 1536;   // 2*I_
constexpr int NBLK = 256;   // persistent grid (1 block/CU co-resident)
constexpr int NTHR = 512;

using bf16x8 = __attribute__((ext_vector_type(8))) short;
using f32x4  = __attribute__((ext_vector_type(4))) float;
typedef unsigned short u16;
typedef unsigned int   u32;

// ---------------- workspace layout (bytes) ----------------
constexpr size_t OFF_TE   = 0;                                   // u16 [B_*S_][H_]  tanh(enc_proj)
constexpr size_t OFF_EMB  = OFF_TE   + (size_t)B_*S_*H_*2;       // u16 [B_*S_][I_]  embeds bf16
constexpr size_t OFF_WDEC = OFF_EMB  + (size_t)B_*S_*I_*2;       // u16 [H_][H_]
constexpr size_t OFF_WHH  = OFF_WDEC + (size_t)H_*H_*2;          // u16 [2][G4H][H_]
constexpr size_t OFF_WIL  = OFF_WHH  + (size_t)2*G4H*H_*2;       // u16 [2][G4H][I_] Wih cols 0..767
constexpr size_t OFF_WIR  = OFF_WIL  + (size_t)2*G4H*I_*2;       // u16 [2][G4H][I_] Wih cols 768..1535
constexpr size_t OFF_WENC = OFF_WIR  + (size_t)2*G4H*I_*2;       // u16 [H_][I_]
constexpr size_t OFF_H    = OFF_WENC + (size_t)H_*I_*2;          // u16 [R_][H_]   h state (bf16)
constexpr size_t OFF_C    = OFF_H    + (size_t)R_*H_*2;          // f32 [R_][H_]   c state
constexpr size_t OFF_TD   = OFF_C    + (size_t)R_*H_*4;          // f32 [R_][H_]   tanh(dec)
constexpr size_t OFF_HWH  = OFF_TD   + (size_t)R_*H_*4;          // f32 [R_][G4H]  h @ Whh^T
constexpr size_t OFF_XW   = OFF_HWH  + (size_t)R_*G4H*4;         // f32 [R_][G4H]  x_t @ WihR^T
constexpr size_t OFF_CTX  = OFF_XW   + (size_t)R_*G4H*4;         // f32 [R_][I_]   unnormalized ctx
constexpr size_t OFF_SUME = OFF_CTX  + (size_t)R_*I_*4;          // f32 [R_]
constexpr size_t OFF_M    = OFF_SUME + 256;                      // f32 [R_] running logsumexp shift
// barrier: bar[32] = generation word; bar[64 + b*32] = block b's arrival flag
// (one 128B line per block -> plain coherent stores, NO RMW contention).
constexpr size_t OFF_BAR  = OFF_M    + 256;
constexpr int    BAR_W    = 64 + NBLK*32;                        // 8256 u32 words
constexpr size_t WS_NEED  = OFF_BAR + BAR_W*4;

// ---------------- helpers ----------------
DEVINL float asf(u32 u){ union{u32 i; float f;} x; x.i=u; return x.f; }
DEVINL u32   asu(float f){ union{u32 i; float f;} x; x.f=f; return x.i; }
DEVINL float bf2f(u16 h){ return asf((u32)h << 16); }
DEVINL u16   f2bf(float f){ u32 u = asu(f); return (u16)((u + 0x7fffu + ((u>>16)&1u)) >> 16); }
DEVINL float frcp(float x){
#if __has_builtin(__builtin_amdgcn_rcpf)
  return __builtin_amdgcn_rcpf(x);
#else
  return 1.0f/x;
#endif
}
DEVINL float sigm(float x){ return frcp(1.0f + __expf(-x)); }

// per-access coherent (sc0 sc1) ops: read/write the IC coherence point
// directly -> no agent-scope fences (no L2 writeback/invalidate) needed.
DEVINL float ldc_f(const float* p){ return __hip_atomic_load(p, __ATOMIC_RELAXED, __HIP_MEMORY_SCOPE_AGENT); }
DEVINL void  stc_f(float* p, float v){ __hip_atomic_store(p, v, __ATOMIC_RELAXED, __HIP_MEMORY_SCOPE_AGENT); }
DEVINL u32   ldc_u(const u32* p){ return __hip_atomic_load(p, __ATOMIC_RELAXED, __HIP_MEMORY_SCOPE_AGENT); }
DEVINL void  stc_u(u32* p, u32 v){ __hip_atomic_store(p, v, __ATOMIC_RELAXED, __HIP_MEMORY_SCOPE_AGENT); }
DEVINL void  addc_f(float* p, float v){ __hip_atomic_fetch_add(p, v, __ATOMIC_RELAXED, __HIP_MEMORY_SCOPE_AGENT); }

// grid barrier v3, contention-free: arrival = plain coherent store to the
// block's OWN cacheline (no RMW serialization — R4-R7's tree barrier spent
// ~10-15us/barrier on 32 serialized RMWs at its root line). Block 0's 256
// threads poll the 256 flag lines IN PARALLEL, then publish the generation;
// everyone else spins on the single generation line (read-only, cheap).
DEVINL void gridbar(u32* bar, u32 n){
  __syncthreads();   // drains vmcnt -> this block's sc-stores are at IC
  if (threadIdx.x == 0)
    stc_u(&bar[64 + blockIdx.x*32], n);           // own line: no contention
  if (blockIdx.x == 0){
    if (threadIdx.x < NBLK){
      while (ldc_u(&bar[64 + threadIdx.x*32]) < n)
        __builtin_amdgcn_s_sleep(1);
    }
    __syncthreads();                               // all 256 flags seen
    if (threadIdx.x == 0) stc_u(&bar[32], n);      // publish generation
  } else {
    if (threadIdx.x == 0){
      while (ldc_u(&bar[32]) < n)
        __builtin_amdgcn_s_sleep(1);
    }
  }
  __syncthreads();
}

// M=16 GEMM over K=512 with A = 16 rows of h (coherent loads, batched 32
// dwords ahead of use) and B = pinned LDS panel [16][520].
DEVINL f32x4 gemm_h16(const u32* h32, size_t base, const u16 (*W)[520], int lr, int lkb){
  f32x4 acc = {0.f,0.f,0.f,0.f};
  #pragma unroll
  for (int half = 0; half < 2; ++half){
    u32 hreg[32];
    #pragma unroll
    for (int i2 = 0; i2 < 32; ++i2)
      hreg[i2] = ldc_u(h32 + base + half*128 + (i2>>2)*16 + (i2&3));
    #pragma unroll
    for (int ki = 0; ki < 8; ++ki){
      union { bf16x8 v; u32 w[4]; } ua;
      ua.w[0]=hreg[ki*4+0]; ua.w[1]=hreg[ki*4+1];
      ua.w[2]=hreg[ki*4+2]; ua.w[3]=hreg[ki*4+3];
      bf16x8 b = *(const bf16x8*)(&W[lr][(half*8+ki)*32 + lkb]);
      acc = __builtin_amdgcn_mfma_f32_16x16x32_bf16(ua.v, b, acc, 0, 0, 0);
    }
  }
  return acc;
}

// ---------------- shared-memory union (phase-transient) ----------------
struct SMemB { float ldsE[2][2][32]; float cpart[4][96][16]; };           // 25088 B
struct SMemC { u16 Abuf[16][776]; float Gpre[32][16]; float Gs[32][16];
               float Hb[16][8]; float inv[16]; float sum[16]; };          // 29568 B
union alignas(16) SMem { SMemB b; SMemC c; };

// ---------------- one-time setup: zero state, convert weights ----------------
__global__ void k_setup(char* ws, const float* Wenc, const float* Wdec,
                        const float* Whh_f, const float* Whh_b,
                        const float* Wih_f, const float* Wih_b,
                        float* out){
  int tid = blockIdx.x*blockDim.x + threadIdx.x;
  int nth = gridDim.x*blockDim.x;
  for (int i = tid; i < B_*S_*C_; i += nth) out[i] = 0.f;
  u16* hB = (u16*)(ws+OFF_H);
  for (int i = tid; i < R_*H_; i += nth) hB[i] = 0;
  float* cS = (float*)(ws+OFF_C);
  for (int i = tid; i < R_*H_; i += nth) cS[i] = 0.f;
  float* mb = (float*)(ws+OFF_M);
  for (int i = tid; i < R_; i += nth) mb[i] = 0.f;
  u32* bar = (u32*)(ws+OFF_BAR);
  for (int i = tid; i < BAR_W; i += nth) bar[i] = 0u;
  u16* wd = (u16*)(ws+OFF_WDEC);
  for (int i = tid; i < H_*H_; i += nth) wd[i] = f2bf(Wdec[i]);
  u16* we = (u16*)(ws+OFF_WENC);
  for (int i = tid; i < H_*I_; i += nth) we[i] = f2bf(Wenc[i]);
  u16* wh = (u16*)(ws+OFF_WHH);
  for (int i = tid; i < G4H*H_; i += nth){
    wh[i] = f2bf(Whh_f[i]);
    wh[G4H*H_ + i] = f2bf(Whh_b[i]);
  }
  u16* wl = (u16*)(ws+OFF_WIL);
  u16* wr = (u16*)(ws+OFF_WIR);
  for (int i = tid; i < G4H*I_; i += nth){
    int n = i / I_, k = i - n*I_;
    wl[i]            = f2bf(Wih_f[n*I2_ + k]);
    wr[i]            = f2bf(Wih_f[n*I2_ + I_ + k]);
    wl[G4H*I_ + i]   = f2bf(Wih_b[n*I2_ + k]);
    wr[G4H*I_ + i]   = f2bf(Wih_b[n*I2_ + I_ + k]);
  }
}

// ---------------- one-time: embeds -> bf16 ----------------
__global__ void k_embconv(char* ws, const float* emb){
  u16* e = (u16*)(ws+OFF_EMB);
  int tid = blockIdx.x*blockDim.x + threadIdx.x;
  int nth = gridDim.x*blockDim.x;
  int n4 = (B_*S_*I_)/4;
  const float4* src = (const float4*)emb;
  ushort4* dst = (ushort4*)e;
  for (int i = tid; i < n4; i += nth){
    float4 x = src[i];
    ushort4 o;
    o.x = f2bf(x.x); o.y = f2bf(x.y); o.z = f2bf(x.z); o.w = f2bf(x.w);
    dst[i] = o;
  }
}

// ---------------- one-time: Te = tanh(embB @ WencB^T + benc) ----------------
__global__ __launch_bounds__(256) void k_enc(char* ws, const float* benc){
  const u16* A = (const u16*)(ws+OFF_EMB);
  const u16* W = (const u16*)(ws+OFF_WENC);
  u16* Te = (u16*)(ws+OFF_TE);
  int wg = blockIdx.x;
  int mt = wg >> 3, ng = wg & 7;
  int wave = threadIdx.x >> 6, lane = threadIdx.x & 63;
  int m0 = mt*16, n0 = ng*64 + wave*16;
  int lr = lane & 15, lkb = (lane>>4)*8;
  const u16* ap = A + (size_t)(m0+lr)*I_ + lkb;
  const u16* bp = W + (size_t)(n0+lr)*I_ + lkb;
  f32x4 acc = {0.f,0.f,0.f,0.f};
  for (int k = 0; k < I_; k += 32){
    bf16x8 a = *(const bf16x8*)(ap + k);
    bf16x8 b = *(const bf16x8*)(bp + k);
    acc = __builtin_amdgcn_mfma_f32_16x16x32_bf16(a, b, acc, 0, 0, 0);
  }
  int row4 = (lane>>4)*4;
  #pragma unroll
  for (int q = 0; q < 4; q++){
    int rr = m0 + row4 + q, cc = n0 + lr;
    Te[(size_t)rr*H_ + cc] = f2bf(tanhf(acc[q] + benc[cc]));
  }
}

// ---------------- persistent stepper: weight-stationary, fence-free sync ----------------
__global__ __launch_bounds__(NTHR) void k_persist(char* ws,
        const float* bdec, const float* v,
        const float* bih_f, const float* bhh_f,
        const float* bih_b, const float* bhh_b,
        const float* Wout, const float* bout, float* out){
  __shared__ SMem sh;
  __shared__ alignas(16) u16 wWhh[16][520];   // (dirA,n0A): Whh rows n0A*16..+15
  __shared__ alignas(16) u16 wWIR[16][776];   // (dirA,n0A): WihR rows n0A*16..+15
  __shared__ alignas(16) u16 wDec[16][520];   // blk<32: Wdec rows blk*16..+15
  __shared__ alignas(16) u16 wWIL[32][776];   // (dirC,ncC): packed [g*8+j] = WihL row g*512+ncC*8+j
  __shared__ float wOutL[10][8];
  __shared__ float bsumL[32];
  u32* bar = (u32*)(ws+OFF_BAR);
  u32 gen = 0;
  const int tid = threadIdx.x, lane = tid & 63, wave = tid >> 6;
  const int lr = lane & 15, lkb = (lane>>4)*8, row4 = (lane>>4)*4;
  const int blk = blockIdx.x;
  const int dirA = blk & 1, n0A = blk >> 1;
  const int ab   = blk & 31, pair = blk >> 5;
  const int s0A  = pair*32, s0B = S_ - pair*32 - 32;
  const int h0   = lane*8;
  const int cg   = (tid < 384) ? (tid % 96) : 0;
  const int rq   = (tid < 384) ? (tid / 96) : 0;
  const int dirC = blk >> 7, ncC = (blk >> 1) & 63, qbC = blk & 1;

  // ---- prologue: pin weights into LDS ----
  { const u16* src = (const u16*)(ws+OFF_WHH) + (size_t)dirA*G4H*H_ + (size_t)n0A*16*H_;
    for (int idx = tid; idx < 16*64; idx += NTHR){ int r = idx>>6, c8 = idx&63;
      *(uint4*)&wWhh[r][c8*8] = *(const uint4*)(src + (size_t)r*H_ + c8*8); } }
  { const u16* src = (const u16*)(ws+OFF_WIR) + (size_t)dirA*G4H*I_ + (size_t)n0A*16*I_;
    for (int idx = tid; idx < 16*96; idx += NTHR){ int r = idx/96, c8 = idx - r*96;
      *(uint4*)&wWIR[r][c8*8] = *(const uint4*)(src + (size_t)r*I_ + c8*8); } }
  if (blk < 32){
    const u16* src = (const u16*)(ws+OFF_WDEC) + (size_t)blk*16*H_;
    for (int idx = tid; idx < 16*64; idx += NTHR){ int r = idx>>6, c8 = idx&63;
      *(uint4*)&wDec[r][c8*8] = *(const uint4*)(src + (size_t)r*H_ + c8*8); } }
  { const u16* src = (const u16*)(ws+OFF_WIL) + (size_t)dirC*G4H*I_;
    for (int idx = tid; idx < 32*96; idx += NTHR){ int pr = idx/96, c8 = idx - pr*96;
      int g = pr>>3, j = pr&7;
      *(uint4*)&wWIL[pr][c8*8] = *(const uint4*)(src + (size_t)(g*512 + ncC*8 + j)*I_ + c8*8); } }
  { const float* bihp = dirC ? bih_b : bih_f;
    const float* bhhp = dirC ? bhh_b : bhh_f;
    if (tid < 32){ int g = tid>>3, c = tid&7; int n = g*512 + ncC*8 + c;
      bsumL[tid] = bihp[n] + bhhp[n]; }
    if (tid >= 64 && tid < 144){ int q = tid-64; int cc = q>>3, c = q&7;
      wOutL[cc][c] = Wout[(size_t)cc*1024 + dirC*512 + ncC*8 + c]; } }
  // Te slice -> 32 VGPRs
  bf16x8 teR[8];
  { const u16* Te = (const u16*)(ws+OFF_TE);
    #pragma unroll
    for (int k = 0; k < 8; ++k){
      int r = wave + 8*k; int ci = r >> 5, u = r & 31;
      int s = (ci ? s0B : s0A) + u;
      teR[k] = *(const bf16x8*)(Te + ((size_t)(ab*S_ + s))*H_ + h0); } }
  // EMB slice -> 64 VGPRs (tid<384)
  bf16x8 embR[16];
  if (tid < 384){
    const u16* E = (const u16*)(ws+OFF_EMB);
    #pragma unroll
    for (int j = 0; j < 16; ++j){
      int r = rq*16 + j;
      int s = (r < 32) ? (s0A + r) : (s0B + (r - 32));
      embR[j] = *(const bf16x8*)(E + ((size_t)(ab*S_ + s))*I_ + cg*8); } }
  __syncthreads();

  for (int t = 0; t < S_; ++t){
    // ===== phase A: dec/Td, h@Whh^T (coherent h loads); zero ctx/sumE =====
    {
      const u32* h32 = (const u32*)(ws+OFF_H);
      if (wave < 2){                 // Whh tile
        int m0 = dirA*32 + wave*16;
        size_t base = (((size_t)(m0+lr))*H_ + lkb) >> 1;
        f32x4 acc = gemm_h16(h32, base, wWhh, lr, lkb);
        float* o = (float*)(ws+OFF_HWH);
        #pragma unroll
        for (int q = 0; q < 4; q++)
          stc_f(&o[(size_t)(m0 + row4 + q)*G4H + n0A*16 + lr], acc[q]);
      } else if (wave < 4){          // WIR tile (EMB is immutable -> plain loads)
        int bbase = (wave-2)*16;
        int trow = dirA ? (S_-1-t) : t;
        const u16* E = (const u16*)(ws+OFF_EMB);
        const u16* ap = E + ((size_t)(bbase+lr)*S_ + trow)*I_ + lkb;
        f32x4 acc = {0.f,0.f,0.f,0.f};
        for (int k = 0; k < I_; k += 32){
          bf16x8 a = *(const bf16x8*)(ap + k);
          bf16x8 b = *(const bf16x8*)(&wWIR[lr][k + lkb]);
          acc = __builtin_amdgcn_mfma_f32_16x16x32_bf16(a, b, acc, 0, 0, 0);
        }
        float* o = (float*)(ws+OFF_XW);
        #pragma unroll
        for (int q = 0; q < 4; q++)
          stc_f(&o[(size_t)(dirA*32 + bbase + row4 + q)*G4H + n0A*16 + lr], acc[q]);
      } else if (blk < 32){          // dec tile
        int m0 = (wave-4)*16;
        size_t base = (((size_t)(m0+lr))*H_ + lkb) >> 1;
        f32x4 acc = gemm_h16(h32, base, wDec, lr, lkb);
        float* Td = (float*)(ws+OFF_TD);
        #pragma unroll
        for (int q = 0; q < 4; q++){
          int rr = m0 + row4 + q, cc = blk*16 + lr;
          stc_f(&Td[rr*H_ + cc], tanhf(acc[q] + bdec[cc]));
        }
      } else {                       // zero ctx & sumE
        int zid = (((blk-32)<<2) + (wave-4))*64 + lane;
        float* ctx = (float*)(ws+OFF_CTX);
        if (zid < R_*I_) stc_f(&ctx[zid], 0.f);
        if (zid < R_) stc_f((float*)(ws+OFF_SUME) + zid, 0.f);
      }
    }
    gridbar(bar, ++gen);
    // ===== phase B: scores (tanh-identity, Te in regs), exp, ctx gather =====
    {
      const float* Td = (const float*)(ws+OFF_TD);
      const float* mbp = (const float*)(ws+OFF_M);
      float tdf[8], tdb[8], va[8];
      #pragma unroll
      for (int j = 0; j < 8; j++){
        tdf[j] = ldc_f(&Td[ab*H_ + h0 + j]);
        tdb[j] = ldc_f(&Td[(32+ab)*H_ + h0 + j]);
        va[j]  = v[h0 + j];
      }
      float mF = ldc_f(&mbp[ab]), mB = ldc_f(&mbp[32+ab]);
      #pragma unroll
      for (int k = 0; k < 8; ++k){
        int r = wave + 8*k;
        int ci = r >> 5, u = r & 31;
        bf16x8 tv = teR[k];
        float af = 0.f, ab2 = 0.f;
        #pragma unroll
        for (int j = 0; j < 8; ++j){
          float te = bf2f((u16)tv[j]);
          float df = fmaf(te, tdf[j], 1.0f);
          float db = fmaf(te, tdb[j], 1.0f);
          af  = fmaf((te+tdf[j])*frcp(df), va[j], af);
          ab2 = fmaf((te+tdb[j])*frcp(db), va[j], ab2);
        }
        #pragma unroll
        for (int off = 1; off < 64; off <<= 1){
          af  += __shfl_xor(af, off);
          ab2 += __shfl_xor(ab2, off);
        }
        float ef = __expf(fminf(fmaxf(af  - mF, -80.f), 80.f));
        float eb = __expf(fminf(fmaxf(ab2 - mB, -80.f), 80.f));
        if (lane == 0){ sh.b.ldsE[0][ci][u] = ef; sh.b.ldsE[1][ci][u] = eb; }
      }
      __syncthreads();
      if (tid < 2){
        float s = 0.f;
        for (int ci = 0; ci < 2; ci++)
          for (int u = 0; u < 32; u++) s += sh.b.ldsE[tid][ci][u];
        addc_f((float*)(ws+OFF_SUME) + tid*32 + ab, s);
      }
      if (tid < 384){
        const int ci = rq >> 1;
        float cf[8] = {0,0,0,0,0,0,0,0}, cb[8] = {0,0,0,0,0,0,0,0};
        #pragma unroll
        for (int j = 0; j < 16; ++j){
          int u = ((rq & 1) << 4) + j;
          float wf = sh.b.ldsE[0][ci][u];
          float wb = sh.b.ldsE[1][1-ci][31-u];
          bf16x8 e = embR[j];
          #pragma unroll
          for (int x = 0; x < 8; ++x){
            float ev = bf2f((u16)e[x]);
            cf[x] = fmaf(wf, ev, cf[x]);
            cb[x] = fmaf(wb, ev, cb[x]);
          }
        }
        #pragma unroll
        for (int x = 0; x < 8; ++x){
          sh.b.cpart[rq][cg][x]   = cf[x];
          sh.b.cpart[rq][cg][8+x] = cb[x];
        }
      }
      __syncthreads();
      {
        float* ctxg = (float*)(ws+OFF_CTX);
        for (int o = tid; o < 1536; o += NTHR){
          int d = (o >= 768) ? 1 : 0;
          int col = o - d*768;
          int cgx = col >> 3, c = col & 7;
          float s = sh.b.cpart[0][cgx][d*8+c] + sh.b.cpart[1][cgx][d*8+c]
                  + sh.b.cpart[2][cgx][d*8+c] + sh.b.cpart[3][cgx][d*8+c];
          addc_f(&ctxg[(size_t)(d*32+ab)*I_ + col], s);
        }
      }
    }
    gridbar(bar, ++gen);
    // ===== phase C: ctx@WihL^T (LDS weights), LSTM cell, out projection =====
    {
      const float* se = (const float*)(ws+OFF_SUME) + dirC*32 + qbC*16;
      if (tid < 16){
        float s_ = ldc_f(&se[tid]);
        sh.c.sum[tid] = s_;
        sh.c.inv[tid] = 1.0f / fmaxf(s_, 1e-30f);
      }
      __syncthreads();
      {  // batched coherent ctx read: thread t owns row t/32, cols (t%32)*24..+23
        const float* ctx = (const float*)(ws+OFF_CTX) + (size_t)(dirC*32 + qbC*16)*I_;
        float creg[24];
        int j = tid >> 5, k0 = (tid & 31) * 24;
        #pragma unroll
        for (int i2 = 0; i2 < 24; ++i2)
          creg[i2] = ldc_f(ctx + (size_t)j*I_ + k0 + i2);
        float inv = sh.c.inv[j];
        #pragma unroll
        for (int i2 = 0; i2 < 24; ++i2)
          sh.c.Abuf[j][k0 + i2] = f2bf(creg[i2] * inv);
      }
      __syncthreads();
      f32x4 acc = {0.f,0.f,0.f,0.f};
      if (wave < 2){                 // GEMM: M=16 batches, N=32 packed gate-rows, K=768
        for (int k = 0; k < I_; k += 32){
          bf16x8 av = *(const bf16x8*)(&sh.c.Abuf[lr][k + lkb]);
          bf16x8 bv = *(const bf16x8*)(&wWIL[wave*16 + lr][k + lkb]);
          acc = __builtin_amdgcn_mfma_f32_16x16x32_bf16(av, bv, acc, 0, 0, 0);
        }
      } else {                       // Gpre = xW + hW + biases
        const float* xW = (const float*)(ws+OFF_XW);
        const float* hW = (const float*)(ws+OFF_HWH);
        for (int ii = tid - 128; ii < 512; ii += 384){
          int pr = ii >> 4, j = ii & 15;
          int g = pr >> 3, c = pr & 7;
          int n = g*512 + ncC*8 + c;
          size_t rr = (size_t)(dirC*32 + qbC*16 + j);
          sh.c.Gpre[pr][j] = ldc_f(&xW[rr*G4H + n]) + ldc_f(&hW[rr*G4H + n]) + bsumL[pr];
        }
      }
      __syncthreads();
      if (wave < 2){
        int pr = wave*16 + lr;
        #pragma unroll
        for (int q = 0; q < 4; q++){
          int j = row4 + q;
          sh.c.Gs[pr][j] = acc[q] + sh.c.Gpre[pr][j];
        }
      }
      __syncthreads();
      float* cS = (float*)(ws+OFF_C);
      if (tid < 128){
        int j = tid >> 3, c = tid & 7;
        int hg = ncC*8 + c;
        size_t rr = (size_t)(dirC*32 + qbC*16 + j);
        float ig = sigm(sh.c.Gs[c][j]);
        float fg = sigm(sh.c.Gs[8+c][j]);
        float gg = tanhf(sh.c.Gs[16+c][j]);
        float og = sigm(sh.c.Gs[24+c][j]);
        float cn = fmaf(fg, cS[rr*H_ + hg], ig*gg);   // cS block-private: plain ok
        float hn = og * tanhf(cn);
        cS[rr*H_ + hg] = cn;
        sh.c.Hb[j][c] = hn;
      }
      __syncthreads();
      if (tid < 64){   // publish h as packed u32 coherent stores
        int j = tid >> 2, cp = tid & 3;
        size_t rr = (size_t)(dirC*32 + qbC*16 + j);
        u32 pk = (u32)f2bf(sh.c.Hb[j][cp*2]) | ((u32)f2bf(sh.c.Hb[j][cp*2+1]) << 16);
        stc_u((u32*)(ws+OFF_H) + ((rr*H_ + ncC*8) >> 1) + cp, pk);
      }
      if (tid < 160){
        int j = tid/10, cc = tid - j*10;
        float s = 0.f;
        #pragma unroll
        for (int c = 0; c < 8; c++) s = fmaf(sh.c.Hb[j][c], wOutL[cc][c], s);
        if (dirC == 0 && ncC == 0) s += bout[cc];
        int bb = qbC*16 + j;
        int st = dirC ? (S_-1-t) : t;
        atomicAdd(&out[((size_t)bb*S_ + st)*C_ + cc], s);
      }
      if (ncC == 0 && tid < 16){
        float* mp = (float*)(ws+OFF_M) + dirC*32 + qbC*16 + tid;
        stc_f(mp, ldc_f(mp) + logf(fmaxf(sh.c.sum[tid], 1e-30f)));
      }
    }
    gridbar(bar, ++gen);
  }
}

// ---------------- host launcher ----------------
extern "C" void kernel_launch(void* const* d_in, const int* in_sizes, int n_in,
                              void* d_out, int out_size, void* d_ws, size_t ws_size,
                              hipStream_t stream){
  const float* emb   = (const float*)d_in[0];
  const float* Wenc  = (const float*)d_in[1];
  const float* benc  = (const float*)d_in[2];
  const float* Wdec  = (const float*)d_in[3];
  const float* bdec  = (const float*)d_in[4];
  const float* v     = (const float*)d_in[5];
  const float* Wih_f = (const float*)d_in[6];
  const float* Whh_f = (const float*)d_in[7];
  const float* bih_f = (const float*)d_in[8];
  const float* bhh_f = (const float*)d_in[9];
  const float* Wih_b = (const float*)d_in[10];
  const float* Whh_b = (const float*)d_in[11];
  const float* bih_b = (const float*)d_in[12];
  const float* bhh_b = (const float*)d_in[13];
  const float* Wout  = (const float*)d_in[14];
  const float* bout  = (const float*)d_in[15];
  float* out = (float*)d_out;
  char* ws = (char*)d_ws;
  if (ws_size < WS_NEED) return;   // fail loudly via validation

  k_setup<<<dim3(512), dim3(256), 0, stream>>>(ws, Wenc, Wdec, Whh_f, Whh_b, Wih_f, Wih_b, out);
  k_embconv<<<dim3(2048), dim3(256), 0, stream>>>(ws, emb);
  k_enc<<<dim3(8192), dim3(256), 0, stream>>>(ws, benc);
  k_persist<<<dim3(NBLK), dim3(NTHR), 0, stream>>>(ws, bdec, v,
      bih_f, bhh_f, bih_b, bhh_b, Wout, bout, out);
}